// Round 1
// baseline (1342.285 us; speedup 1.0000x reference)
//
#include <hip/hip_runtime.h>

#define N_NODES 100000
#define N_EDGES 1600000
#define F_IN 64
#define HIDDEN 128
#define N_GRAPHS 1024
#define EPS 1e-5f

// ---------------------------------------------------------------------------
// CSR build: histogram of dst -> exclusive scan -> scatter edges sorted by dst
// ---------------------------------------------------------------------------

__global__ __launch_bounds__(256) void hist_kernel(const int* __restrict__ ei,
                                                   int* __restrict__ hist) {
    int e = blockIdx.x * 256 + threadIdx.x;
    if (e < N_EDGES) atomicAdd(&hist[ei[N_EDGES + e]], 1);
}

// Single-block exclusive scan over N_NODES. hist_pos: in=histogram,
// out=exclusive scan (running scatter positions). rowptr gets the same +
// rowptr[N_NODES]=E.
__global__ __launch_bounds__(1024) void scan_kernel(int* __restrict__ hist_pos,
                                                    int* __restrict__ rowptr) {
    __shared__ int lds[1024];
    __shared__ int s_carry;
    int t = threadIdx.x;
    if (t == 0) s_carry = 0;
    __syncthreads();
    for (int base = 0; base < N_NODES; base += 1024) {
        int i = base + t;
        int v = (i < N_NODES) ? hist_pos[i] : 0;
        lds[t] = v;
        __syncthreads();
        #pragma unroll
        for (int off = 1; off < 1024; off <<= 1) {
            int x = (t >= off) ? lds[t - off] : 0;
            __syncthreads();
            lds[t] += x;
            __syncthreads();
        }
        int incl  = lds[t];
        int total = lds[1023];
        int excl  = incl - v + s_carry;
        if (i < N_NODES) { rowptr[i] = excl; hist_pos[i] = excl; }
        __syncthreads();
        if (t == 0) s_carry += total;
        __syncthreads();
    }
    if (t == 0) rowptr[N_NODES] = s_carry;
}

__global__ __launch_bounds__(256) void scatter_kernel(const int* __restrict__ ei,
                                                      const float* __restrict__ ea,
                                                      int* __restrict__ pos,
                                                      int* __restrict__ src_s,
                                                      float* __restrict__ ew_s) {
    int e = blockIdx.x * 256 + threadIdx.x;
    if (e < N_EDGES) {
        int d = ei[N_EDGES + e];
        int p = atomicAdd(&pos[d], 1);
        src_s[p] = ei[e];
        ew_s[p] = ea[e];
    }
}

// ---------------------------------------------------------------------------
// Aggregation: one 64-lane wave per node, lane = feature (x1 or x2).
// agg[n][f] = sum over incoming edges e: h[src[e]][f] * ew[e]
// ---------------------------------------------------------------------------

template <int F>
__global__ __launch_bounds__(256) void agg_kernel(const float* __restrict__ h,
                                                  const int* __restrict__ rowptr,
                                                  const int* __restrict__ src_s,
                                                  const float* __restrict__ ew_s,
                                                  float* __restrict__ agg) {
    int node = blockIdx.x * 4 + (threadIdx.x >> 6);
    if (node >= N_NODES) return;
    int lane = threadIdx.x & 63;
    constexpr int PER = F / 64;  // 1 (F=64) or 2 (F=128)
    float acc[PER];
    #pragma unroll
    for (int j = 0; j < PER; ++j) acc[j] = 0.f;
    int beg = rowptr[node], end = rowptr[node + 1];
    for (int e = beg; e < end; ++e) {
        int   s = src_s[e];
        float w = ew_s[e];
        #pragma unroll
        for (int j = 0; j < PER; ++j)
            acc[j] = fmaf(h[(size_t)s * F + lane + j * 64], w, acc[j]);
    }
    #pragma unroll
    for (int j = 0; j < PER; ++j)
        agg[(size_t)node * F + lane + j * 64] = acc[j];
}

// ---------------------------------------------------------------------------
// Fused GEMM + bias + BN + ReLU:
//   out[r][c] = relu( BN( agg[r]@W0[:,c] + h[r]@W1[:,c] + bias[c] ) )
// Treated as single GEMM with K = 2F. Tile 64 rows x 64 cols, 256 threads,
// 4x4 microtile per thread, K-chunks of 16, A stored transposed in LDS.
// ---------------------------------------------------------------------------

template <int F>
__global__ __launch_bounds__(256) void gemm_bn_relu(const float* __restrict__ A0,   // agg, stride F
                                                    const float* __restrict__ A1,   // h,   stride F
                                                    const float* __restrict__ W0,   // (F,128)
                                                    const float* __restrict__ W1,   // (F,128)
                                                    const float* __restrict__ bias,
                                                    const float* __restrict__ bng,
                                                    const float* __restrict__ bnb,
                                                    const float* __restrict__ bnm,
                                                    const float* __restrict__ bnv,
                                                    float* __restrict__ out) {      // stride 128
    constexpr int KC = 16;
    __shared__ float As[KC][68];  // [k][row], +4 pad
    __shared__ float Ws[KC][68];  // [k][col]

    int t = threadIdx.x;
    int rowbase = blockIdx.x * 64;
    int colbase = blockIdx.y * 64;

    int arow = t >> 2;          // 0..63
    int ak4  = (t & 3) * 4;     // 0,4,8,12
    int wkb  = t >> 6;          // 0..3
    int wc   = t & 63;          // 0..63
    int tr   = t >> 4;          // 0..15
    int tc   = t & 15;          // 0..15

    float acc[4][4] = {};

    for (int kc = 0; kc < 2 * F; kc += KC) {
        const float* Ap = (kc < F) ? A0 : A1;
        const float* Wp = (kc < F) ? W0 : W1;
        int kof = (kc < F) ? kc : kc - F;

        {  // load A tile, transpose into LDS
            int r = rowbase + arow;
            float4 v4 = make_float4(0.f, 0.f, 0.f, 0.f);
            if (r < N_NODES)
                v4 = *(const float4*)(Ap + (size_t)r * F + kof + ak4);
            As[ak4 + 0][arow] = v4.x;
            As[ak4 + 1][arow] = v4.y;
            As[ak4 + 2][arow] = v4.z;
            As[ak4 + 3][arow] = v4.w;
        }
        #pragma unroll
        for (int i = 0; i < 4; ++i) {  // load W tile
            int k = wkb + i * 4;
            Ws[k][wc] = Wp[(size_t)(kof + k) * 128 + colbase + wc];
        }
        __syncthreads();

        #pragma unroll
        for (int k = 0; k < KC; ++k) {
            float4 a = *(const float4*)&As[k][tr * 4];
            float4 w = *(const float4*)&Ws[k][tc * 4];
            acc[0][0] = fmaf(a.x, w.x, acc[0][0]);
            acc[0][1] = fmaf(a.x, w.y, acc[0][1]);
            acc[0][2] = fmaf(a.x, w.z, acc[0][2]);
            acc[0][3] = fmaf(a.x, w.w, acc[0][3]);
            acc[1][0] = fmaf(a.y, w.x, acc[1][0]);
            acc[1][1] = fmaf(a.y, w.y, acc[1][1]);
            acc[1][2] = fmaf(a.y, w.z, acc[1][2]);
            acc[1][3] = fmaf(a.y, w.w, acc[1][3]);
            acc[2][0] = fmaf(a.z, w.x, acc[2][0]);
            acc[2][1] = fmaf(a.z, w.y, acc[2][1]);
            acc[2][2] = fmaf(a.z, w.z, acc[2][2]);
            acc[2][3] = fmaf(a.z, w.w, acc[2][3]);
            acc[3][0] = fmaf(a.w, w.x, acc[3][0]);
            acc[3][1] = fmaf(a.w, w.y, acc[3][1]);
            acc[3][2] = fmaf(a.w, w.z, acc[3][2]);
            acc[3][3] = fmaf(a.w, w.w, acc[3][3]);
        }
        __syncthreads();
    }

    // epilogue: bias + BN + relu, float4 stores
    float sc[4], sh[4], bi[4];
    #pragma unroll
    for (int j = 0; j < 4; ++j) {
        int c = colbase + tc * 4 + j;
        sc[j] = bng[c] * rsqrtf(bnv[c] + EPS);
        sh[j] = bnb[c] - bnm[c] * sc[j];
        bi[j] = bias[c];
    }
    #pragma unroll
    for (int i = 0; i < 4; ++i) {
        int r = rowbase + tr * 4 + i;
        if (r < N_NODES) {
            float4 o4;
            o4.x = fmaxf(fmaf(acc[i][0] + bi[0], sc[0], sh[0]), 0.f);
            o4.y = fmaxf(fmaf(acc[i][1] + bi[1], sc[1], sh[1]), 0.f);
            o4.z = fmaxf(fmaf(acc[i][2] + bi[2], sc[2], sh[2]), 0.f);
            o4.w = fmaxf(fmaf(acc[i][3] + bi[3], sc[3], sh[3]), 0.f);
            *(float4*)(out + (size_t)r * 128 + colbase + tc * 4) = o4;
        }
    }
}

// ---------------------------------------------------------------------------
// Pooling: sum per graph + counts (batch is sorted but atomics are fine here)
// ---------------------------------------------------------------------------

__global__ __launch_bounds__(256) void pool_kernel(const float* __restrict__ h,
                                                   const int* __restrict__ batch,
                                                   float* __restrict__ pooled,
                                                   float* __restrict__ cnt) {
    int idx = blockIdx.x * 256 + threadIdx.x;  // over N_NODES*128
    if (idx >= N_NODES * 128) return;
    int node = idx >> 7;
    int f    = idx & 127;
    int g    = batch[node];
    atomicAdd(&pooled[(size_t)g * 128 + f], h[idx]);
    if (f == 0) atomicAdd(&cnt[g], 1.0f);
}

// ---------------------------------------------------------------------------
// Head: out[g] = (relu(mean_row @ W1 + b1)) @ W2 + b2. One wave per graph.
// ---------------------------------------------------------------------------

__global__ __launch_bounds__(64) void head_kernel(const float* __restrict__ pooled,
                                                  const float* __restrict__ cnt,
                                                  const float* __restrict__ w1,  // (128,64)
                                                  const float* __restrict__ b1,
                                                  const float* __restrict__ w2,  // (64,1)
                                                  const float* __restrict__ b2,
                                                  float* __restrict__ out) {
    int g = blockIdx.x;
    int j = threadIdx.x;  // hidden unit 0..63
    float inv = 1.0f / fmaxf(cnt[g], 1.0f);
    float acc = b1[j];
    #pragma unroll 4
    for (int k = 0; k < 128; ++k)
        acc = fmaf(pooled[(size_t)g * 128 + k] * inv, w1[k * 64 + j], acc);
    float prod = fmaxf(acc, 0.f) * w2[j];
    #pragma unroll
    for (int off = 32; off > 0; off >>= 1)
        prod += __shfl_down(prod, off);
    if (j == 0) out[g] = prod + b2[0];
}

// ---------------------------------------------------------------------------

extern "C" void kernel_launch(void* const* d_in, const int* in_sizes, int n_in,
                              void* d_out, int out_size, void* d_ws, size_t ws_size,
                              hipStream_t stream) {
    const float* x     = (const float*)d_in[0];
    const int*   ei    = (const int*)d_in[1];
    const float* ea    = (const float*)d_in[2];
    const int*   batch = (const int*)d_in[3];
    const float* rel_w[3]  = {(const float*)d_in[4],  (const float*)d_in[11], (const float*)d_in[18]};
    const float* rel_b[3]  = {(const float*)d_in[5],  (const float*)d_in[12], (const float*)d_in[19]};
    const float* root_w[3] = {(const float*)d_in[6],  (const float*)d_in[13], (const float*)d_in[20]};
    const float* bn_g[3]   = {(const float*)d_in[7],  (const float*)d_in[14], (const float*)d_in[21]};
    const float* bn_b[3]   = {(const float*)d_in[8],  (const float*)d_in[15], (const float*)d_in[22]};
    const float* bn_m[3]   = {(const float*)d_in[9],  (const float*)d_in[16], (const float*)d_in[23]};
    const float* bn_v[3]   = {(const float*)d_in[10], (const float*)d_in[17], (const float*)d_in[24]};
    const float* head_w1 = (const float*)d_in[25];
    const float* head_b1 = (const float*)d_in[26];
    const float* head_w2 = (const float*)d_in[27];
    const float* head_b2 = (const float*)d_in[28];
    float* out = (float*)d_out;

    // workspace layout (256B-aligned offsets), total ~167.8 MB
    char* ws = (char*)d_ws;
    int*   rowptr = (int*)(ws + 0);              // (N_NODES+1) ints
    int*   pos    = (int*)(ws + 400128);         // N_NODES ints (hist -> positions)
    int*   src_s  = (int*)(ws + 800256);         // E ints
    float* ew_s   = (float*)(ws + 7200256);      // E floats
    float* h_a    = (float*)(ws + 13600256);     // N*128
    float* h_b    = (float*)(ws + 64800256);     // N*128
    float* agg    = (float*)(ws + 116000256);    // N*128 (layer0 uses N*64)
    float* pooled = (float*)(ws + 167200256);    // 1024*128
    float* cnt    = pooled + N_GRAPHS * HIDDEN;  // 1024

    // CSR build (reused by all 3 layers)
    hipMemsetAsync(pos, 0, N_NODES * sizeof(int), stream);
    hipMemsetAsync(pooled, 0, (N_GRAPHS * HIDDEN + N_GRAPHS) * sizeof(float), stream);
    hist_kernel<<<(N_EDGES + 255) / 256, 256, 0, stream>>>(ei, pos);
    scan_kernel<<<1, 1024, 0, stream>>>(pos, rowptr);
    scatter_kernel<<<(N_EDGES + 255) / 256, 256, 0, stream>>>(ei, ea, pos, src_s, ew_s);

    const int AGG_BLOCKS  = (N_NODES + 3) / 4;
    const dim3 GEMM_GRID((N_NODES + 63) / 64, 2);

    // layer 0: F=64 -> h_a
    agg_kernel<64><<<AGG_BLOCKS, 256, 0, stream>>>(x, rowptr, src_s, ew_s, agg);
    gemm_bn_relu<64><<<GEMM_GRID, 256, 0, stream>>>(agg, x, rel_w[0], root_w[0], rel_b[0],
                                                    bn_g[0], bn_b[0], bn_m[0], bn_v[0], h_a);
    // layer 1: F=128 -> h_b
    agg_kernel<128><<<AGG_BLOCKS, 256, 0, stream>>>(h_a, rowptr, src_s, ew_s, agg);
    gemm_bn_relu<128><<<GEMM_GRID, 256, 0, stream>>>(agg, h_a, rel_w[1], root_w[1], rel_b[1],
                                                     bn_g[1], bn_b[1], bn_m[1], bn_v[1], h_b);
    // layer 2: F=128 -> h_a
    agg_kernel<128><<<AGG_BLOCKS, 256, 0, stream>>>(h_b, rowptr, src_s, ew_s, agg);
    gemm_bn_relu<128><<<GEMM_GRID, 256, 0, stream>>>(agg, h_b, rel_w[2], root_w[2], rel_b[2],
                                                     bn_g[2], bn_b[2], bn_m[2], bn_v[2], h_a);

    // pooling + head
    pool_kernel<<<(N_NODES * 128 + 255) / 256, 256, 0, stream>>>(h_a, batch, pooled, cnt);
    head_kernel<<<N_GRAPHS, 64, 0, stream>>>(pooled, cnt, head_w1, head_b1, head_w2, head_b2, out);
}

// Round 2
// 1059.445 us; speedup vs baseline: 1.2670x; 1.2670x over previous
//
#include <hip/hip_runtime.h>

#define N_NODES 100000
#define N_EDGES 1600000
#define F_IN 64
#define HIDDEN 128
#define N_GRAPHS 1024
#define EPS 1e-5f

#define SCAN_BLOCK 1024
#define SCAN_TILES ((N_NODES + SCAN_BLOCK - 1) / SCAN_BLOCK)  // 98

// ---------------------------------------------------------------------------
// CSR build: histogram of dst -> hierarchical exclusive scan -> scatter
// ---------------------------------------------------------------------------

__global__ __launch_bounds__(256) void hist_kernel(const int* __restrict__ ei,
                                                   int* __restrict__ hist) {
    int e = blockIdx.x * 256 + threadIdx.x;
    if (e < N_EDGES) atomicAdd(&hist[ei[N_EDGES + e]], 1);
}

// per-tile sums (grid = SCAN_TILES)
__global__ __launch_bounds__(256) void tile_reduce_kernel(const int* __restrict__ hist,
                                                          int* __restrict__ tilesums) {
    __shared__ int lds[4];
    int b = blockIdx.x, t = threadIdx.x;
    int base = b * SCAN_BLOCK;
    int v = 0;
    #pragma unroll
    for (int i = 0; i < SCAN_BLOCK / 256; ++i) {
        int idx = base + t + i * 256;
        if (idx < N_NODES) v += hist[idx];
    }
    #pragma unroll
    for (int off = 32; off > 0; off >>= 1) v += __shfl_down(v, off);
    if ((t & 63) == 0) lds[t >> 6] = v;
    __syncthreads();
    if (t == 0) tilesums[b] = lds[0] + lds[1] + lds[2] + lds[3];
}

// exclusive scan of the SCAN_TILES tile sums (single small block)
__global__ __launch_bounds__(128) void scan_sums_kernel(int* __restrict__ tilesums,
                                                        int* __restrict__ rowptr) {
    __shared__ int lds[128];
    int t = threadIdx.x;
    int v = (t < SCAN_TILES) ? tilesums[t] : 0;
    lds[t] = v;
    __syncthreads();
    #pragma unroll
    for (int off = 1; off < 128; off <<= 1) {
        int x = (t >= off) ? lds[t - off] : 0;
        __syncthreads();
        lds[t] += x;
        __syncthreads();
    }
    if (t < SCAN_TILES) tilesums[t] = lds[t] - v;  // exclusive
    if (t == 0) rowptr[N_NODES] = lds[127];        // grand total = N_EDGES
}

// per-tile scan + tile offset -> rowptr & scatter positions (grid = SCAN_TILES)
__global__ __launch_bounds__(1024) void tile_scan_kernel(const int* __restrict__ hist,
                                                         const int* __restrict__ tilesums,
                                                         int* __restrict__ rowptr,
                                                         int* __restrict__ pos) {
    __shared__ int lds[SCAN_BLOCK];
    int b = blockIdx.x, t = threadIdx.x;
    int i = b * SCAN_BLOCK + t;
    int v = (i < N_NODES) ? hist[i] : 0;
    lds[t] = v;
    __syncthreads();
    #pragma unroll
    for (int off = 1; off < SCAN_BLOCK; off <<= 1) {
        int x = (t >= off) ? lds[t - off] : 0;
        __syncthreads();
        lds[t] += x;
        __syncthreads();
    }
    if (i < N_NODES) {
        int excl = lds[t] - v + tilesums[b];
        rowptr[i] = excl;
        pos[i] = excl;
    }
}

__global__ __launch_bounds__(256) void scatter_kernel(const int* __restrict__ ei,
                                                      const float* __restrict__ ea,
                                                      int* __restrict__ pos,
                                                      int* __restrict__ src_s,
                                                      float* __restrict__ ew_s) {
    int e = blockIdx.x * 256 + threadIdx.x;
    if (e < N_EDGES) {
        int d = ei[N_EDGES + e];
        int p = atomicAdd(&pos[d], 1);
        src_s[p] = ei[e];
        ew_s[p] = ea[e];
    }
}

// ---------------------------------------------------------------------------
// Aggregation: one 64-lane wave per node, lane = feature (x1 or x2).
// ---------------------------------------------------------------------------

template <int F>
__global__ __launch_bounds__(256) void agg_kernel(const float* __restrict__ h,
                                                  const int* __restrict__ rowptr,
                                                  const int* __restrict__ src_s,
                                                  const float* __restrict__ ew_s,
                                                  float* __restrict__ agg) {
    int node = blockIdx.x * 4 + (threadIdx.x >> 6);
    if (node >= N_NODES) return;
    int lane = threadIdx.x & 63;
    constexpr int PER = F / 64;
    float acc[PER];
    #pragma unroll
    for (int j = 0; j < PER; ++j) acc[j] = 0.f;
    int beg = rowptr[node], end = rowptr[node + 1];
    for (int e = beg; e < end; ++e) {
        int   s = src_s[e];
        float w = ew_s[e];
        #pragma unroll
        for (int j = 0; j < PER; ++j)
            acc[j] = fmaf(h[(size_t)s * F + lane + j * 64], w, acc[j]);
    }
    #pragma unroll
    for (int j = 0; j < PER; ++j)
        agg[(size_t)node * F + lane + j * 64] = acc[j];
}

// ---------------------------------------------------------------------------
// Fused GEMM + bias + BN + ReLU (K = 2F): 64x64 tile, 4x4 microtile
// ---------------------------------------------------------------------------

template <int F>
__global__ __launch_bounds__(256) void gemm_bn_relu(const float* __restrict__ A0,
                                                    const float* __restrict__ A1,
                                                    const float* __restrict__ W0,
                                                    const float* __restrict__ W1,
                                                    const float* __restrict__ bias,
                                                    const float* __restrict__ bng,
                                                    const float* __restrict__ bnb,
                                                    const float* __restrict__ bnm,
                                                    const float* __restrict__ bnv,
                                                    float* __restrict__ out) {
    constexpr int KC = 16;
    __shared__ float As[KC][68];
    __shared__ float Ws[KC][68];

    int t = threadIdx.x;
    int rowbase = blockIdx.x * 64;
    int colbase = blockIdx.y * 64;

    int arow = t >> 2;
    int ak4  = (t & 3) * 4;
    int wkb  = t >> 6;
    int wc   = t & 63;
    int tr   = t >> 4;
    int tc   = t & 15;

    float acc[4][4] = {};

    for (int kc = 0; kc < 2 * F; kc += KC) {
        const float* Ap = (kc < F) ? A0 : A1;
        const float* Wp = (kc < F) ? W0 : W1;
        int kof = (kc < F) ? kc : kc - F;

        {
            int r = rowbase + arow;
            float4 v4 = make_float4(0.f, 0.f, 0.f, 0.f);
            if (r < N_NODES)
                v4 = *(const float4*)(Ap + (size_t)r * F + kof + ak4);
            As[ak4 + 0][arow] = v4.x;
            As[ak4 + 1][arow] = v4.y;
            As[ak4 + 2][arow] = v4.z;
            As[ak4 + 3][arow] = v4.w;
        }
        #pragma unroll
        for (int i = 0; i < 4; ++i) {
            int k = wkb + i * 4;
            Ws[k][wc] = Wp[(size_t)(kof + k) * 128 + colbase + wc];
        }
        __syncthreads();

        #pragma unroll
        for (int k = 0; k < KC; ++k) {
            float4 a = *(const float4*)&As[k][tr * 4];
            float4 w = *(const float4*)&Ws[k][tc * 4];
            acc[0][0] = fmaf(a.x, w.x, acc[0][0]);
            acc[0][1] = fmaf(a.x, w.y, acc[0][1]);
            acc[0][2] = fmaf(a.x, w.z, acc[0][2]);
            acc[0][3] = fmaf(a.x, w.w, acc[0][3]);
            acc[1][0] = fmaf(a.y, w.x, acc[1][0]);
            acc[1][1] = fmaf(a.y, w.y, acc[1][1]);
            acc[1][2] = fmaf(a.y, w.z, acc[1][2]);
            acc[1][3] = fmaf(a.y, w.w, acc[1][3]);
            acc[2][0] = fmaf(a.z, w.x, acc[2][0]);
            acc[2][1] = fmaf(a.z, w.y, acc[2][1]);
            acc[2][2] = fmaf(a.z, w.z, acc[2][2]);
            acc[2][3] = fmaf(a.z, w.w, acc[2][3]);
            acc[3][0] = fmaf(a.w, w.x, acc[3][0]);
            acc[3][1] = fmaf(a.w, w.y, acc[3][1]);
            acc[3][2] = fmaf(a.w, w.z, acc[3][2]);
            acc[3][3] = fmaf(a.w, w.w, acc[3][3]);
        }
        __syncthreads();
    }

    float sc[4], sh[4], bi[4];
    #pragma unroll
    for (int j = 0; j < 4; ++j) {
        int c = colbase + tc * 4 + j;
        sc[j] = bng[c] * rsqrtf(bnv[c] + EPS);
        sh[j] = bnb[c] - bnm[c] * sc[j];
        bi[j] = bias[c];
    }
    #pragma unroll
    for (int i = 0; i < 4; ++i) {
        int r = rowbase + tr * 4 + i;
        if (r < N_NODES) {
            float4 o4;
            o4.x = fmaxf(fmaf(acc[i][0] + bi[0], sc[0], sh[0]), 0.f);
            o4.y = fmaxf(fmaf(acc[i][1] + bi[1], sc[1], sh[1]), 0.f);
            o4.z = fmaxf(fmaf(acc[i][2] + bi[2], sc[2], sh[2]), 0.f);
            o4.w = fmaxf(fmaf(acc[i][3] + bi[3], sc[3], sh[3]), 0.f);
            *(float4*)(out + (size_t)r * 128 + colbase + tc * 4) = o4;
        }
    }
}

// ---------------------------------------------------------------------------
// Pooling: batch is sorted -> run-length accumulate, flush 1 atomic per run.
// Block covers 64 nodes; thread t: feature t&127, node parity t>>7.
// ---------------------------------------------------------------------------

#define POOL_NODES 64
__global__ __launch_bounds__(256) void pool_kernel(const float* __restrict__ h,
                                                   const int* __restrict__ batch,
                                                   float* __restrict__ pooled) {
    __shared__ int gb[POOL_NODES];
    int b = blockIdx.x, t = threadIdx.x;
    int n0 = b * POOL_NODES;
    if (t < POOL_NODES) {
        int n = n0 + t;
        gb[t] = (n < N_NODES) ? batch[n] : -1;
    }
    __syncthreads();
    int f = t & 127;
    int half = t >> 7;
    float acc = 0.f;
    int gcur = -1;
    for (int i = half; i < POOL_NODES; i += 2) {
        int n = n0 + i;
        if (n >= N_NODES) break;
        int g = gb[i];
        if (g != gcur) {
            if (gcur >= 0) atomicAdd(&pooled[(size_t)gcur * 128 + f], acc);
            gcur = g;
            acc = 0.f;
        }
        acc += h[(size_t)n * 128 + f];
    }
    if (gcur >= 0) atomicAdd(&pooled[(size_t)gcur * 128 + f], acc);
}

// ---------------------------------------------------------------------------
// Head: counts via binary search on sorted batch (no atomics), wave per graph
// ---------------------------------------------------------------------------

__global__ __launch_bounds__(64) void head_kernel(const float* __restrict__ pooled,
                                                  const int* __restrict__ batch,
                                                  const float* __restrict__ w1,
                                                  const float* __restrict__ b1,
                                                  const float* __restrict__ w2,
                                                  const float* __restrict__ b2,
                                                  float* __restrict__ out) {
    int g = blockIdx.x;
    int j = threadIdx.x;
    // lower/upper bound of g in sorted batch (uniform across wave; broadcast loads)
    int lo = 0, hi = N_NODES;
    while (lo < hi) { int m = (lo + hi) >> 1; if (batch[m] <  g) lo = m + 1; else hi = m; }
    int start = lo;
    lo = 0; hi = N_NODES;
    while (lo < hi) { int m = (lo + hi) >> 1; if (batch[m] <= g) lo = m + 1; else hi = m; }
    float inv = 1.0f / fmaxf((float)(lo - start), 1.0f);

    float acc = b1[j];
    #pragma unroll 4
    for (int k = 0; k < 128; ++k)
        acc = fmaf(pooled[(size_t)g * 128 + k] * inv, w1[k * 64 + j], acc);
    float prod = fmaxf(acc, 0.f) * w2[j];
    #pragma unroll
    for (int off = 32; off > 0; off >>= 1)
        prod += __shfl_down(prod, off);
    if (j == 0) out[g] = prod + b2[0];
}

// ---------------------------------------------------------------------------

extern "C" void kernel_launch(void* const* d_in, const int* in_sizes, int n_in,
                              void* d_out, int out_size, void* d_ws, size_t ws_size,
                              hipStream_t stream) {
    const float* x     = (const float*)d_in[0];
    const int*   ei    = (const int*)d_in[1];
    const float* ea    = (const float*)d_in[2];
    const int*   batch = (const int*)d_in[3];
    const float* rel_w[3]  = {(const float*)d_in[4],  (const float*)d_in[11], (const float*)d_in[18]};
    const float* rel_b[3]  = {(const float*)d_in[5],  (const float*)d_in[12], (const float*)d_in[19]};
    const float* root_w[3] = {(const float*)d_in[6],  (const float*)d_in[13], (const float*)d_in[20]};
    const float* bn_g[3]   = {(const float*)d_in[7],  (const float*)d_in[14], (const float*)d_in[21]};
    const float* bn_b[3]   = {(const float*)d_in[8],  (const float*)d_in[15], (const float*)d_in[22]};
    const float* bn_m[3]   = {(const float*)d_in[9],  (const float*)d_in[16], (const float*)d_in[23]};
    const float* bn_v[3]   = {(const float*)d_in[10], (const float*)d_in[17], (const float*)d_in[24]};
    const float* head_w1 = (const float*)d_in[25];
    const float* head_b1 = (const float*)d_in[26];
    const float* head_w2 = (const float*)d_in[27];
    const float* head_b2 = (const float*)d_in[28];
    float* out = (float*)d_out;

    // workspace layout (same footprint as R1; hist/tilesums alias agg region)
    char* ws = (char*)d_ws;
    int*   rowptr  = (int*)(ws + 0);             // N_NODES+1 ints
    int*   pos     = (int*)(ws + 400384);        // N_NODES ints
    int*   src_s   = (int*)(ws + 800768);        // E ints
    float* ew_s    = (float*)(ws + 7200768);     // E floats
    float* h_a     = (float*)(ws + 13600768);    // N*128
    float* h_b     = (float*)(ws + 64800768);    // N*128
    float* agg     = (float*)(ws + 116000768);   // N*128 (layer0 uses N*64)
    float* pooled  = (float*)(ws + 167200768);   // 1024*128
    // hist & tilesums only live before the first agg_kernel -> alias agg region
    int*   hist     = (int*)agg;                 // N_NODES ints
    int*   tilesums = (int*)(ws + 116000768 + 1048576);  // SCAN_TILES ints

    hipMemsetAsync(hist, 0, N_NODES * sizeof(int), stream);
    hipMemsetAsync(pooled, 0, N_GRAPHS * HIDDEN * sizeof(float), stream);

    hist_kernel<<<(N_EDGES + 255) / 256, 256, 0, stream>>>(ei, hist);
    tile_reduce_kernel<<<SCAN_TILES, 256, 0, stream>>>(hist, tilesums);
    scan_sums_kernel<<<1, 128, 0, stream>>>(tilesums, rowptr);
    tile_scan_kernel<<<SCAN_TILES, SCAN_BLOCK, 0, stream>>>(hist, tilesums, rowptr, pos);
    scatter_kernel<<<(N_EDGES + 255) / 256, 256, 0, stream>>>(ei, ea, pos, src_s, ew_s);

    const int AGG_BLOCKS = (N_NODES + 3) / 4;
    const dim3 GEMM_GRID((N_NODES + 63) / 64, 2);

    agg_kernel<64><<<AGG_BLOCKS, 256, 0, stream>>>(x, rowptr, src_s, ew_s, agg);
    gemm_bn_relu<64><<<GEMM_GRID, 256, 0, stream>>>(agg, x, rel_w[0], root_w[0], rel_b[0],
                                                    bn_g[0], bn_b[0], bn_m[0], bn_v[0], h_a);
    agg_kernel<128><<<AGG_BLOCKS, 256, 0, stream>>>(h_a, rowptr, src_s, ew_s, agg);
    gemm_bn_relu<128><<<GEMM_GRID, 256, 0, stream>>>(agg, h_a, rel_w[1], root_w[1], rel_b[1],
                                                     bn_g[1], bn_b[1], bn_m[1], bn_v[1], h_b);
    agg_kernel<128><<<AGG_BLOCKS, 256, 0, stream>>>(h_b, rowptr, src_s, ew_s, agg);
    gemm_bn_relu<128><<<GEMM_GRID, 256, 0, stream>>>(agg, h_b, rel_w[2], root_w[2], rel_b[2],
                                                     bn_g[2], bn_b[2], bn_m[2], bn_v[2], h_a);

    pool_kernel<<<(N_NODES + POOL_NODES - 1) / POOL_NODES, 256, 0, stream>>>(h_a, batch, pooled);
    head_kernel<<<N_GRAPHS, 64, 0, stream>>>(pooled, batch, head_w1, head_b1, head_w2, head_b2, out);
}

// Round 3
// 894.200 us; speedup vs baseline: 1.5011x; 1.1848x over previous
//
#include <hip/hip_runtime.h>

#define N_NODES 100000
#define N_EDGES 1600000
#define F_IN 64
#define HIDDEN 128
#define N_GRAPHS 1024
#define EPS 1e-5f

#define SCAN_BLOCK 1024
#define SCAN_TILES ((N_NODES + SCAN_BLOCK - 1) / SCAN_BLOCK)  // 98

// ---------------------------------------------------------------------------
// CSR build: histogram of dst -> hierarchical exclusive scan -> scatter
// ---------------------------------------------------------------------------

__global__ __launch_bounds__(256) void hist_kernel(const int* __restrict__ ei,
                                                   int* __restrict__ hist) {
    int e = blockIdx.x * 256 + threadIdx.x;
    if (e < N_EDGES) atomicAdd(&hist[ei[N_EDGES + e]], 1);
}

__global__ __launch_bounds__(256) void tile_reduce_kernel(const int* __restrict__ hist,
                                                          int* __restrict__ tilesums) {
    __shared__ int lds[4];
    int b = blockIdx.x, t = threadIdx.x;
    int base = b * SCAN_BLOCK;
    int v = 0;
    #pragma unroll
    for (int i = 0; i < SCAN_BLOCK / 256; ++i) {
        int idx = base + t + i * 256;
        if (idx < N_NODES) v += hist[idx];
    }
    #pragma unroll
    for (int off = 32; off > 0; off >>= 1) v += __shfl_down(v, off);
    if ((t & 63) == 0) lds[t >> 6] = v;
    __syncthreads();
    if (t == 0) tilesums[b] = lds[0] + lds[1] + lds[2] + lds[3];
}

__global__ __launch_bounds__(128) void scan_sums_kernel(int* __restrict__ tilesums,
                                                        int* __restrict__ rowptr) {
    __shared__ int lds[128];
    int t = threadIdx.x;
    int v = (t < SCAN_TILES) ? tilesums[t] : 0;
    lds[t] = v;
    __syncthreads();
    #pragma unroll
    for (int off = 1; off < 128; off <<= 1) {
        int x = (t >= off) ? lds[t - off] : 0;
        __syncthreads();
        lds[t] += x;
        __syncthreads();
    }
    if (t < SCAN_TILES) tilesums[t] = lds[t] - v;
    if (t == 0) rowptr[N_NODES] = lds[127];
}

__global__ __launch_bounds__(1024) void tile_scan_kernel(const int* __restrict__ hist,
                                                         const int* __restrict__ tilesums,
                                                         int* __restrict__ rowptr,
                                                         int* __restrict__ pos) {
    __shared__ int lds[SCAN_BLOCK];
    int b = blockIdx.x, t = threadIdx.x;
    int i = b * SCAN_BLOCK + t;
    int v = (i < N_NODES) ? hist[i] : 0;
    lds[t] = v;
    __syncthreads();
    #pragma unroll
    for (int off = 1; off < SCAN_BLOCK; off <<= 1) {
        int x = (t >= off) ? lds[t - off] : 0;
        __syncthreads();
        lds[t] += x;
        __syncthreads();
    }
    if (i < N_NODES) {
        int excl = lds[t] - v + tilesums[b];
        rowptr[i] = excl;
        pos[i] = excl;
    }
}

// edge metadata packed: {src, ew as bits} -> one 8B broadcast load per edge
__global__ __launch_bounds__(256) void scatter_kernel(const int* __restrict__ ei,
                                                      const float* __restrict__ ea,
                                                      int* __restrict__ pos,
                                                      int2* __restrict__ em) {
    int e = blockIdx.x * 256 + threadIdx.x;
    if (e < N_EDGES) {
        int d = ei[N_EDGES + e];
        int p = atomicAdd(&pos[d], 1);
        em[p] = make_int2(ei[e], __float_as_int(ea[e]));
    }
}

// ---------------------------------------------------------------------------
// Aggregation: one 64-lane wave per node, lane covers PER contiguous features
// (float2 at lane*2 for F=128 -> single 512B transaction per row gather).
// 4-edge unroll, 4 independent accumulators -> 4 gathers in flight per wave.
// ---------------------------------------------------------------------------

template <int F>
__global__ __launch_bounds__(256) void agg_kernel(const float* __restrict__ h,
                                                  const int* __restrict__ rowptr,
                                                  const int2* __restrict__ em,
                                                  float* __restrict__ agg) {
    int node = blockIdx.x * 4 + (threadIdx.x >> 6);
    int lane = threadIdx.x & 63;
    constexpr int PER = F / 64;  // 1 or 2
    float a0[PER] = {}, a1[PER] = {}, a2[PER] = {}, a3[PER] = {};
    int beg = rowptr[node], end = rowptr[node + 1];
    int e = beg;
    for (; e + 4 <= end; e += 4) {
        int2 m0 = em[e], m1 = em[e + 1], m2 = em[e + 2], m3 = em[e + 3];
        const float* p0 = h + (size_t)m0.x * F + lane * PER;
        const float* p1 = h + (size_t)m1.x * F + lane * PER;
        const float* p2 = h + (size_t)m2.x * F + lane * PER;
        const float* p3 = h + (size_t)m3.x * F + lane * PER;
        if (PER == 2) {
            float2 v0 = *(const float2*)p0;
            float2 v1 = *(const float2*)p1;
            float2 v2 = *(const float2*)p2;
            float2 v3 = *(const float2*)p3;
            float w0 = __int_as_float(m0.y), w1 = __int_as_float(m1.y);
            float w2 = __int_as_float(m2.y), w3 = __int_as_float(m3.y);
            a0[0] = fmaf(v0.x, w0, a0[0]); a0[1] = fmaf(v0.y, w0, a0[1]);
            a1[0] = fmaf(v1.x, w1, a1[0]); a1[1] = fmaf(v1.y, w1, a1[1]);
            a2[0] = fmaf(v2.x, w2, a2[0]); a2[1] = fmaf(v2.y, w2, a2[1]);
            a3[0] = fmaf(v3.x, w3, a3[0]); a3[1] = fmaf(v3.y, w3, a3[1]);
        } else {
            float v0 = *p0, v1 = *p1, v2 = *p2, v3 = *p3;
            a0[0] = fmaf(v0, __int_as_float(m0.y), a0[0]);
            a1[0] = fmaf(v1, __int_as_float(m1.y), a1[0]);
            a2[0] = fmaf(v2, __int_as_float(m2.y), a2[0]);
            a3[0] = fmaf(v3, __int_as_float(m3.y), a3[0]);
        }
    }
    for (; e < end; ++e) {
        int2 m = em[e];
        float w = __int_as_float(m.y);
        const float* p = h + (size_t)m.x * F + lane * PER;
        #pragma unroll
        for (int j = 0; j < PER; ++j) a0[j] = fmaf(p[j], w, a0[j]);
    }
    #pragma unroll
    for (int j = 0; j < PER; ++j)
        agg[(size_t)node * F + lane * PER + j] = (a0[j] + a1[j]) + (a2[j] + a3[j]);
}

// ---------------------------------------------------------------------------
// Fused GEMM + bias + BN + ReLU (K = 2F): 64x64 tile, 4x4 microtile
// ---------------------------------------------------------------------------

template <int F>
__global__ __launch_bounds__(256) void gemm_bn_relu(const float* __restrict__ A0,
                                                    const float* __restrict__ A1,
                                                    const float* __restrict__ W0,
                                                    const float* __restrict__ W1,
                                                    const float* __restrict__ bias,
                                                    const float* __restrict__ bng,
                                                    const float* __restrict__ bnb,
                                                    const float* __restrict__ bnm,
                                                    const float* __restrict__ bnv,
                                                    float* __restrict__ out) {
    constexpr int KC = 16;
    __shared__ float As[KC][68];
    __shared__ float Ws[KC][68];

    int t = threadIdx.x;
    int rowbase = blockIdx.x * 64;
    int colbase = blockIdx.y * 64;

    int arow = t >> 2;
    int ak4  = (t & 3) * 4;
    int wkb  = t >> 6;
    int wc   = t & 63;
    int tr   = t >> 4;
    int tc   = t & 15;

    float acc[4][4] = {};

    for (int kc = 0; kc < 2 * F; kc += KC) {
        const float* Ap = (kc < F) ? A0 : A1;
        const float* Wp = (kc < F) ? W0 : W1;
        int kof = (kc < F) ? kc : kc - F;

        {
            int r = rowbase + arow;
            float4 v4 = make_float4(0.f, 0.f, 0.f, 0.f);
            if (r < N_NODES)
                v4 = *(const float4*)(Ap + (size_t)r * F + kof + ak4);
            As[ak4 + 0][arow] = v4.x;
            As[ak4 + 1][arow] = v4.y;
            As[ak4 + 2][arow] = v4.z;
            As[ak4 + 3][arow] = v4.w;
        }
        #pragma unroll
        for (int i = 0; i < 4; ++i) {
            int k = wkb + i * 4;
            Ws[k][wc] = Wp[(size_t)(kof + k) * 128 + colbase + wc];
        }
        __syncthreads();

        #pragma unroll
        for (int k = 0; k < KC; ++k) {
            float4 a = *(const float4*)&As[k][tr * 4];
            float4 w = *(const float4*)&Ws[k][tc * 4];
            acc[0][0] = fmaf(a.x, w.x, acc[0][0]);
            acc[0][1] = fmaf(a.x, w.y, acc[0][1]);
            acc[0][2] = fmaf(a.x, w.z, acc[0][2]);
            acc[0][3] = fmaf(a.x, w.w, acc[0][3]);
            acc[1][0] = fmaf(a.y, w.x, acc[1][0]);
            acc[1][1] = fmaf(a.y, w.y, acc[1][1]);
            acc[1][2] = fmaf(a.y, w.z, acc[1][2]);
            acc[1][3] = fmaf(a.y, w.w, acc[1][3]);
            acc[2][0] = fmaf(a.z, w.x, acc[2][0]);
            acc[2][1] = fmaf(a.z, w.y, acc[2][1]);
            acc[2][2] = fmaf(a.z, w.z, acc[2][2]);
            acc[2][3] = fmaf(a.z, w.w, acc[2][3]);
            acc[3][0] = fmaf(a.w, w.x, acc[3][0]);
            acc[3][1] = fmaf(a.w, w.y, acc[3][1]);
            acc[3][2] = fmaf(a.w, w.z, acc[3][2]);
            acc[3][3] = fmaf(a.w, w.w, acc[3][3]);
        }
        __syncthreads();
    }

    float sc[4], sh[4], bi[4];
    #pragma unroll
    for (int j = 0; j < 4; ++j) {
        int c = colbase + tc * 4 + j;
        sc[j] = bng[c] * rsqrtf(bnv[c] + EPS);
        sh[j] = bnb[c] - bnm[c] * sc[j];
        bi[j] = bias[c];
    }
    #pragma unroll
    for (int i = 0; i < 4; ++i) {
        int r = rowbase + tr * 4 + i;
        if (r < N_NODES) {
            float4 o4;
            o4.x = fmaxf(fmaf(acc[i][0] + bi[0], sc[0], sh[0]), 0.f);
            o4.y = fmaxf(fmaf(acc[i][1] + bi[1], sc[1], sh[1]), 0.f);
            o4.z = fmaxf(fmaf(acc[i][2] + bi[2], sc[2], sh[2]), 0.f);
            o4.w = fmaxf(fmaf(acc[i][3] + bi[3], sc[3], sh[3]), 0.f);
            *(float4*)(out + (size_t)r * 128 + colbase + tc * 4) = o4;
        }
    }
}

// ---------------------------------------------------------------------------
// Pooling: batch sorted -> run-length accumulate, 1 atomic per run per feature
// ---------------------------------------------------------------------------

#define POOL_NODES 64
__global__ __launch_bounds__(256) void pool_kernel(const float* __restrict__ h,
                                                   const int* __restrict__ batch,
                                                   float* __restrict__ pooled) {
    __shared__ int gb[POOL_NODES];
    int b = blockIdx.x, t = threadIdx.x;
    int n0 = b * POOL_NODES;
    if (t < POOL_NODES) {
        int n = n0 + t;
        gb[t] = (n < N_NODES) ? batch[n] : -1;
    }
    __syncthreads();
    int f = t & 127;
    int half = t >> 7;
    float acc = 0.f;
    int gcur = -1;
    for (int i = half; i < POOL_NODES; i += 2) {
        int n = n0 + i;
        if (n >= N_NODES) break;
        int g = gb[i];
        if (g != gcur) {
            if (gcur >= 0) atomicAdd(&pooled[(size_t)gcur * 128 + f], acc);
            gcur = g;
            acc = 0.f;
        }
        acc += h[(size_t)n * 128 + f];
    }
    if (gcur >= 0) atomicAdd(&pooled[(size_t)gcur * 128 + f], acc);
}

// ---------------------------------------------------------------------------
// Head: counts via binary search on sorted batch, one wave per graph
// ---------------------------------------------------------------------------

__global__ __launch_bounds__(64) void head_kernel(const float* __restrict__ pooled,
                                                  const int* __restrict__ batch,
                                                  const float* __restrict__ w1,
                                                  const float* __restrict__ b1,
                                                  const float* __restrict__ w2,
                                                  const float* __restrict__ b2,
                                                  float* __restrict__ out) {
    int g = blockIdx.x;
    int j = threadIdx.x;
    int lo = 0, hi = N_NODES;
    while (lo < hi) { int m = (lo + hi) >> 1; if (batch[m] <  g) lo = m + 1; else hi = m; }
    int start = lo;
    lo = 0; hi = N_NODES;
    while (lo < hi) { int m = (lo + hi) >> 1; if (batch[m] <= g) lo = m + 1; else hi = m; }
    float inv = 1.0f / fmaxf((float)(lo - start), 1.0f);

    float acc = b1[j];
    #pragma unroll 4
    for (int k = 0; k < 128; ++k)
        acc = fmaf(pooled[(size_t)g * 128 + k] * inv, w1[k * 64 + j], acc);
    float prod = fmaxf(acc, 0.f) * w2[j];
    #pragma unroll
    for (int off = 32; off > 0; off >>= 1)
        prod += __shfl_down(prod, off);
    if (j == 0) out[g] = prod + b2[0];
}

// ---------------------------------------------------------------------------

extern "C" void kernel_launch(void* const* d_in, const int* in_sizes, int n_in,
                              void* d_out, int out_size, void* d_ws, size_t ws_size,
                              hipStream_t stream) {
    const float* x     = (const float*)d_in[0];
    const int*   ei    = (const int*)d_in[1];
    const float* ea    = (const float*)d_in[2];
    const int*   batch = (const int*)d_in[3];
    const float* rel_w[3]  = {(const float*)d_in[4],  (const float*)d_in[11], (const float*)d_in[18]};
    const float* rel_b[3]  = {(const float*)d_in[5],  (const float*)d_in[12], (const float*)d_in[19]};
    const float* root_w[3] = {(const float*)d_in[6],  (const float*)d_in[13], (const float*)d_in[20]};
    const float* bn_g[3]   = {(const float*)d_in[7],  (const float*)d_in[14], (const float*)d_in[21]};
    const float* bn_b[3]   = {(const float*)d_in[8],  (const float*)d_in[15], (const float*)d_in[22]};
    const float* bn_m[3]   = {(const float*)d_in[9],  (const float*)d_in[16], (const float*)d_in[23]};
    const float* bn_v[3]   = {(const float*)d_in[10], (const float*)d_in[17], (const float*)d_in[24]};
    const float* head_w1 = (const float*)d_in[25];
    const float* head_b1 = (const float*)d_in[26];
    const float* head_w2 = (const float*)d_in[27];
    const float* head_b2 = (const float*)d_in[28];
    float* out = (float*)d_out;

    char* ws = (char*)d_ws;
    int*   rowptr  = (int*)(ws + 0);             // N_NODES+1 ints
    int*   pos     = (int*)(ws + 400384);        // N_NODES ints
    int2*  em      = (int2*)(ws + 800768);       // E int2 (src, ew bits)
    float* h_a     = (float*)(ws + 13600768);    // N*128
    float* h_b     = (float*)(ws + 64800768);    // N*128
    float* agg     = (float*)(ws + 116000768);   // N*128 (layer0 uses N*64)
    float* pooled  = (float*)(ws + 167200768);   // 1024*128
    int*   hist     = (int*)agg;                 // aliases agg (dead until layer0 agg)
    int*   tilesums = (int*)(ws + 116000768 + 1048576);

    hipMemsetAsync(hist, 0, N_NODES * sizeof(int), stream);
    hipMemsetAsync(pooled, 0, N_GRAPHS * HIDDEN * sizeof(float), stream);

    hist_kernel<<<(N_EDGES + 255) / 256, 256, 0, stream>>>(ei, hist);
    tile_reduce_kernel<<<SCAN_TILES, 256, 0, stream>>>(hist, tilesums);
    scan_sums_kernel<<<1, 128, 0, stream>>>(tilesums, rowptr);
    tile_scan_kernel<<<SCAN_TILES, SCAN_BLOCK, 0, stream>>>(hist, tilesums, rowptr, pos);
    scatter_kernel<<<(N_EDGES + 255) / 256, 256, 0, stream>>>(ei, ea, pos, em);

    const int AGG_BLOCKS = N_NODES / 4;
    const dim3 GEMM_GRID((N_NODES + 63) / 64, 2);

    agg_kernel<64><<<AGG_BLOCKS, 256, 0, stream>>>(x, rowptr, em, agg);
    gemm_bn_relu<64><<<GEMM_GRID, 256, 0, stream>>>(agg, x, rel_w[0], root_w[0], rel_b[0],
                                                    bn_g[0], bn_b[0], bn_m[0], bn_v[0], h_a);
    agg_kernel<128><<<AGG_BLOCKS, 256, 0, stream>>>(h_a, rowptr, em, agg);
    gemm_bn_relu<128><<<GEMM_GRID, 256, 0, stream>>>(agg, h_a, rel_w[1], root_w[1], rel_b[1],
                                                     bn_g[1], bn_b[1], bn_m[1], bn_v[1], h_b);
    agg_kernel<128><<<AGG_BLOCKS, 256, 0, stream>>>(h_b, rowptr, em, agg);
    gemm_bn_relu<128><<<GEMM_GRID, 256, 0, stream>>>(agg, h_b, rel_w[2], root_w[2], rel_b[2],
                                                     bn_g[2], bn_b[2], bn_m[2], bn_v[2], h_a);

    pool_kernel<<<(N_NODES + POOL_NODES - 1) / POOL_NODES, 256, 0, stream>>>(h_a, batch, pooled);
    head_kernel<<<N_GRAPHS, 64, 0, stream>>>(pooled, batch, head_w1, head_b1, head_w2, head_b2, out);
}

// Round 4
// 806.082 us; speedup vs baseline: 1.6652x; 1.1093x over previous
//
#include <hip/hip_runtime.h>

#define N_NODES 100000
#define N_EDGES 1600000
#define F_IN 64
#define HIDDEN 128
#define N_GRAPHS 1024
#define EPS 1e-5f

// two-level counting sort parameters
#define NBLK_A 128
#define CHUNK ((N_EDGES + NBLK_A - 1) / NBLK_A)        // 12500
#define BUCK_SHIFT 9                                    // 512-node windows
#define NBUCK ((N_NODES + 511) / 512)                   // 196
#define SCAN_M (NBUCK * NBLK_A)                         // 25088

// ---------------------------------------------------------------------------
// CSR build via two-level counting sort (no global atomics anywhere)
// ---------------------------------------------------------------------------

// per-(block,bucket) counts, bucket-major
__global__ __launch_bounds__(256) void bin_count_kernel(const int* __restrict__ ei,
                                                        int* __restrict__ counts) {
    __shared__ int cnt[NBUCK];
    int blk = blockIdx.x, t = threadIdx.x;
    for (int i = t; i < NBUCK; i += 256) cnt[i] = 0;
    __syncthreads();
    int e0 = blk * CHUNK, e1 = min(e0 + CHUNK, N_EDGES);
    for (int e = e0 + t; e < e1; e += 256)
        atomicAdd(&cnt[ei[N_EDGES + e] >> BUCK_SHIFT], 1);
    __syncthreads();
    for (int i = t; i < NBUCK; i += 256) counts[i * NBLK_A + blk] = cnt[i];
}

// in-place exclusive scan of the counts matrix (single block)
__global__ __launch_bounds__(1024) void scan_counts_kernel(int* __restrict__ counts,
                                                           int* __restrict__ rowptr) {
    __shared__ int tot[1024];
    const int PT = (SCAN_M + 1023) / 1024;  // 25
    int t = threadIdx.x;
    int base = t * PT;
    int local[PT];
    int s = 0;
    #pragma unroll
    for (int i = 0; i < PT; ++i) {
        int idx = base + i;
        int v = (idx < SCAN_M) ? counts[idx] : 0;
        local[i] = s;
        s += v;
    }
    tot[t] = s;
    __syncthreads();
    int v = s;
    for (int off = 1; off < 1024; off <<= 1) {
        int x = (t >= off) ? tot[t - off] : 0;
        __syncthreads();
        tot[t] += x;
        __syncthreads();
    }
    int excl = tot[t] - v;
    #pragma unroll
    for (int i = 0; i < PT; ++i) {
        int idx = base + i;
        if (idx < SCAN_M) counts[idx] = excl + local[i];
    }
    if (t == 0) rowptr[N_NODES] = N_EDGES;
}

// scatter edges into coarse-bucket order (LDS cursors; contiguous runs)
__global__ __launch_bounds__(256) void bin_scatter_kernel(const int* __restrict__ ei,
                                                          const float* __restrict__ ea,
                                                          const int* __restrict__ counts,
                                                          int* __restrict__ dstb,
                                                          int2* __restrict__ emb) {
    __shared__ int cur[NBUCK];
    int blk = blockIdx.x, t = threadIdx.x;
    for (int i = t; i < NBUCK; i += 256) cur[i] = counts[i * NBLK_A + blk];
    __syncthreads();
    int e0 = blk * CHUNK, e1 = min(e0 + CHUNK, N_EDGES);
    for (int e = e0 + t; e < e1; e += 256) {
        int s = ei[e], d = ei[N_EDGES + e];
        float w = ea[e];
        int p = atomicAdd(&cur[d >> BUCK_SHIFT], 1);
        dstb[p] = d;
        emb[p] = make_int2(s, __float_as_int(w));
    }
}

// per-bucket exact sort + rowptr (LDS hist/scan/cursors; writes stay in-bucket)
__global__ __launch_bounds__(1024) void bucket_build_kernel(const int* __restrict__ counts,
                                                            const int* __restrict__ dstb,
                                                            const int2* __restrict__ emb,
                                                            int* __restrict__ rowptr,
                                                            int2* __restrict__ em) {
    __shared__ int hist[512];
    __shared__ int cursor[512];
    int b = blockIdx.x, t = threadIdx.x;
    int beg = counts[b * NBLK_A];
    int end = (b + 1 < NBUCK) ? counts[(b + 1) * NBLK_A] : N_EDGES;
    int nbase = b << BUCK_SHIFT;
    int nnodes = min(512, N_NODES - nbase);

    if (t < 512) hist[t] = 0;
    __syncthreads();
    for (int e = beg + t; e < end; e += 1024)
        atomicAdd(&hist[dstb[e] & 511], 1);
    __syncthreads();

    int v = (t < 512) ? hist[t] : 0;
    for (int off = 1; off < 512; off <<= 1) {
        int x = (t < 512 && t >= off) ? hist[t - off] : 0;
        __syncthreads();
        if (t < 512) hist[t] += x;
        __syncthreads();
    }
    if (t < 512) {
        int excl = hist[t] - v;
        cursor[t] = beg + excl;
        if (t < nnodes) rowptr[nbase + t] = beg + excl;
    }
    __syncthreads();

    for (int e = beg + t; e < end; e += 1024) {
        int d = dstb[e];
        int2 m = emb[e];
        int p = atomicAdd(&cursor[d & 511], 1);
        em[p] = m;
    }
}

// ---------------------------------------------------------------------------
// Aggregation: one 64-lane wave per node, lane covers PER contiguous features.
// 4-edge unroll, 4 independent accumulators -> 4 gathers in flight per wave.
// ---------------------------------------------------------------------------

template <int F>
__global__ __launch_bounds__(256) void agg_kernel(const float* __restrict__ h,
                                                  const int* __restrict__ rowptr,
                                                  const int2* __restrict__ em,
                                                  float* __restrict__ agg) {
    int node = blockIdx.x * 4 + (threadIdx.x >> 6);
    int lane = threadIdx.x & 63;
    constexpr int PER = F / 64;  // 1 or 2
    float a0[PER] = {}, a1[PER] = {}, a2[PER] = {}, a3[PER] = {};
    int beg = rowptr[node], end = rowptr[node + 1];
    int e = beg;
    for (; e + 4 <= end; e += 4) {
        int2 m0 = em[e], m1 = em[e + 1], m2 = em[e + 2], m3 = em[e + 3];
        const float* p0 = h + (size_t)m0.x * F + lane * PER;
        const float* p1 = h + (size_t)m1.x * F + lane * PER;
        const float* p2 = h + (size_t)m2.x * F + lane * PER;
        const float* p3 = h + (size_t)m3.x * F + lane * PER;
        if (PER == 2) {
            float2 v0 = *(const float2*)p0;
            float2 v1 = *(const float2*)p1;
            float2 v2 = *(const float2*)p2;
            float2 v3 = *(const float2*)p3;
            float w0 = __int_as_float(m0.y), w1 = __int_as_float(m1.y);
            float w2 = __int_as_float(m2.y), w3 = __int_as_float(m3.y);
            a0[0] = fmaf(v0.x, w0, a0[0]); a0[1] = fmaf(v0.y, w0, a0[1]);
            a1[0] = fmaf(v1.x, w1, a1[0]); a1[1] = fmaf(v1.y, w1, a1[1]);
            a2[0] = fmaf(v2.x, w2, a2[0]); a2[1] = fmaf(v2.y, w2, a2[1]);
            a3[0] = fmaf(v3.x, w3, a3[0]); a3[1] = fmaf(v3.y, w3, a3[1]);
        } else {
            float v0 = *p0, v1 = *p1, v2 = *p2, v3 = *p3;
            a0[0] = fmaf(v0, __int_as_float(m0.y), a0[0]);
            a1[0] = fmaf(v1, __int_as_float(m1.y), a1[0]);
            a2[0] = fmaf(v2, __int_as_float(m2.y), a2[0]);
            a3[0] = fmaf(v3, __int_as_float(m3.y), a3[0]);
        }
    }
    for (; e < end; ++e) {
        int2 m = em[e];
        float w = __int_as_float(m.y);
        const float* p = h + (size_t)m.x * F + lane * PER;
        #pragma unroll
        for (int j = 0; j < PER; ++j) a0[j] = fmaf(p[j], w, a0[j]);
    }
    #pragma unroll
    for (int j = 0; j < PER; ++j)
        agg[(size_t)node * F + lane * PER + j] = (a0[j] + a1[j]) + (a2[j] + a3[j]);
}

// ---------------------------------------------------------------------------
// Fused GEMM + bias + BN + ReLU (K = 2F): 64x64 tile, 4x4 microtile
// ---------------------------------------------------------------------------

template <int F>
__global__ __launch_bounds__(256) void gemm_bn_relu(const float* __restrict__ A0,
                                                    const float* __restrict__ A1,
                                                    const float* __restrict__ W0,
                                                    const float* __restrict__ W1,
                                                    const float* __restrict__ bias,
                                                    const float* __restrict__ bng,
                                                    const float* __restrict__ bnb,
                                                    const float* __restrict__ bnm,
                                                    const float* __restrict__ bnv,
                                                    float* __restrict__ out) {
    constexpr int KC = 16;
    __shared__ float As[KC][68];
    __shared__ float Ws[KC][68];

    int t = threadIdx.x;
    int rowbase = blockIdx.x * 64;
    int colbase = blockIdx.y * 64;

    int arow = t >> 2;
    int ak4  = (t & 3) * 4;
    int wkb  = t >> 6;
    int wc   = t & 63;
    int tr   = t >> 4;
    int tc   = t & 15;

    float acc[4][4] = {};

    for (int kc = 0; kc < 2 * F; kc += KC) {
        const float* Ap = (kc < F) ? A0 : A1;
        const float* Wp = (kc < F) ? W0 : W1;
        int kof = (kc < F) ? kc : kc - F;

        {
            int r = rowbase + arow;
            float4 v4 = make_float4(0.f, 0.f, 0.f, 0.f);
            if (r < N_NODES)
                v4 = *(const float4*)(Ap + (size_t)r * F + kof + ak4);
            As[ak4 + 0][arow] = v4.x;
            As[ak4 + 1][arow] = v4.y;
            As[ak4 + 2][arow] = v4.z;
            As[ak4 + 3][arow] = v4.w;
        }
        #pragma unroll
        for (int i = 0; i < 4; ++i) {
            int k = wkb + i * 4;
            Ws[k][wc] = Wp[(size_t)(kof + k) * 128 + colbase + wc];
        }
        __syncthreads();

        #pragma unroll
        for (int k = 0; k < KC; ++k) {
            float4 a = *(const float4*)&As[k][tr * 4];
            float4 w = *(const float4*)&Ws[k][tc * 4];
            acc[0][0] = fmaf(a.x, w.x, acc[0][0]);
            acc[0][1] = fmaf(a.x, w.y, acc[0][1]);
            acc[0][2] = fmaf(a.x, w.z, acc[0][2]);
            acc[0][3] = fmaf(a.x, w.w, acc[0][3]);
            acc[1][0] = fmaf(a.y, w.x, acc[1][0]);
            acc[1][1] = fmaf(a.y, w.y, acc[1][1]);
            acc[1][2] = fmaf(a.y, w.z, acc[1][2]);
            acc[1][3] = fmaf(a.y, w.w, acc[1][3]);
            acc[2][0] = fmaf(a.z, w.x, acc[2][0]);
            acc[2][1] = fmaf(a.z, w.y, acc[2][1]);
            acc[2][2] = fmaf(a.z, w.z, acc[2][2]);
            acc[2][3] = fmaf(a.z, w.w, acc[2][3]);
            acc[3][0] = fmaf(a.w, w.x, acc[3][0]);
            acc[3][1] = fmaf(a.w, w.y, acc[3][1]);
            acc[3][2] = fmaf(a.w, w.z, acc[3][2]);
            acc[3][3] = fmaf(a.w, w.w, acc[3][3]);
        }
        __syncthreads();
    }

    float sc[4], sh[4], bi[4];
    #pragma unroll
    for (int j = 0; j < 4; ++j) {
        int c = colbase + tc * 4 + j;
        sc[j] = bng[c] * rsqrtf(bnv[c] + EPS);
        sh[j] = bnb[c] - bnm[c] * sc[j];
        bi[j] = bias[c];
    }
    #pragma unroll
    for (int i = 0; i < 4; ++i) {
        int r = rowbase + tr * 4 + i;
        if (r < N_NODES) {
            float4 o4;
            o4.x = fmaxf(fmaf(acc[i][0] + bi[0], sc[0], sh[0]), 0.f);
            o4.y = fmaxf(fmaf(acc[i][1] + bi[1], sc[1], sh[1]), 0.f);
            o4.z = fmaxf(fmaf(acc[i][2] + bi[2], sc[2], sh[2]), 0.f);
            o4.w = fmaxf(fmaf(acc[i][3] + bi[3], sc[3], sh[3]), 0.f);
            *(float4*)(out + (size_t)r * 128 + colbase + tc * 4) = o4;
        }
    }
}

// ---------------------------------------------------------------------------
// Pooling: batch sorted -> run-length accumulate, 1 atomic per run per feature
// ---------------------------------------------------------------------------

#define POOL_NODES 64
__global__ __launch_bounds__(256) void pool_kernel(const float* __restrict__ h,
                                                   const int* __restrict__ batch,
                                                   float* __restrict__ pooled) {
    __shared__ int gb[POOL_NODES];
    int b = blockIdx.x, t = threadIdx.x;
    int n0 = b * POOL_NODES;
    if (t < POOL_NODES) {
        int n = n0 + t;
        gb[t] = (n < N_NODES) ? batch[n] : -1;
    }
    __syncthreads();
    int f = t & 127;
    int half = t >> 7;
    float acc = 0.f;
    int gcur = -1;
    for (int i = half; i < POOL_NODES; i += 2) {
        int n = n0 + i;
        if (n >= N_NODES) break;
        int g = gb[i];
        if (g != gcur) {
            if (gcur >= 0) atomicAdd(&pooled[(size_t)gcur * 128 + f], acc);
            gcur = g;
            acc = 0.f;
        }
        acc += h[(size_t)n * 128 + f];
    }
    if (gcur >= 0) atomicAdd(&pooled[(size_t)gcur * 128 + f], acc);
}

// ---------------------------------------------------------------------------
// Head: counts via binary search on sorted batch, one wave per graph
// ---------------------------------------------------------------------------

__global__ __launch_bounds__(64) void head_kernel(const float* __restrict__ pooled,
                                                  const int* __restrict__ batch,
                                                  const float* __restrict__ w1,
                                                  const float* __restrict__ b1,
                                                  const float* __restrict__ w2,
                                                  const float* __restrict__ b2,
                                                  float* __restrict__ out) {
    int g = blockIdx.x;
    int j = threadIdx.x;
    int lo = 0, hi = N_NODES;
    while (lo < hi) { int m = (lo + hi) >> 1; if (batch[m] <  g) lo = m + 1; else hi = m; }
    int start = lo;
    lo = 0; hi = N_NODES;
    while (lo < hi) { int m = (lo + hi) >> 1; if (batch[m] <= g) lo = m + 1; else hi = m; }
    float inv = 1.0f / fmaxf((float)(lo - start), 1.0f);

    float acc = b1[j];
    #pragma unroll 4
    for (int k = 0; k < 128; ++k)
        acc = fmaf(pooled[(size_t)g * 128 + k] * inv, w1[k * 64 + j], acc);
    float prod = fmaxf(acc, 0.f) * w2[j];
    #pragma unroll
    for (int off = 32; off > 0; off >>= 1)
        prod += __shfl_down(prod, off);
    if (j == 0) out[g] = prod + b2[0];
}

// ---------------------------------------------------------------------------

extern "C" void kernel_launch(void* const* d_in, const int* in_sizes, int n_in,
                              void* d_out, int out_size, void* d_ws, size_t ws_size,
                              hipStream_t stream) {
    const float* x     = (const float*)d_in[0];
    const int*   ei    = (const int*)d_in[1];
    const float* ea    = (const float*)d_in[2];
    const int*   batch = (const int*)d_in[3];
    const float* rel_w[3]  = {(const float*)d_in[4],  (const float*)d_in[11], (const float*)d_in[18]};
    const float* rel_b[3]  = {(const float*)d_in[5],  (const float*)d_in[12], (const float*)d_in[19]};
    const float* root_w[3] = {(const float*)d_in[6],  (const float*)d_in[13], (const float*)d_in[20]};
    const float* bn_g[3]   = {(const float*)d_in[7],  (const float*)d_in[14], (const float*)d_in[21]};
    const float* bn_b[3]   = {(const float*)d_in[8],  (const float*)d_in[15], (const float*)d_in[22]};
    const float* bn_m[3]   = {(const float*)d_in[9],  (const float*)d_in[16], (const float*)d_in[23]};
    const float* bn_v[3]   = {(const float*)d_in[10], (const float*)d_in[17], (const float*)d_in[24]};
    const float* head_w1 = (const float*)d_in[25];
    const float* head_b1 = (const float*)d_in[26];
    const float* head_w2 = (const float*)d_in[27];
    const float* head_b2 = (const float*)d_in[28];
    float* out = (float*)d_out;

    // workspace layout (max end ~167.76 MB, same envelope as prior rounds)
    char* ws = (char*)d_ws;
    int*   rowptr = (int*)(ws + 0);              // N_NODES+1 ints
    int*   counts = (int*)(ws + 401408);         // SCAN_M ints (raw -> excl scan)
    int2*  em     = (int2*)(ws + 524288);        // E int2 (src, ew bits) final CSR
    float* h_a    = (float*)(ws + 13631488);     // N*128
    float* h_b    = (float*)(ws + 64831488);     // N*128
    float* agg    = (float*)(ws + 116031488);    // N*128 (layer0 uses N*64)
    float* pooled = (float*)(ws + 167231488);    // 1024*128
    // binned scratch aliases agg (dead until first agg_kernel)
    int*   dstb = (int*)(ws + 116031488);        // E ints
    int2*  emb  = (int2*)(ws + 122431488);       // E int2

    hipMemsetAsync(pooled, 0, N_GRAPHS * HIDDEN * sizeof(float), stream);

    bin_count_kernel<<<NBLK_A, 256, 0, stream>>>(ei, counts);
    scan_counts_kernel<<<1, 1024, 0, stream>>>(counts, rowptr);
    bin_scatter_kernel<<<NBLK_A, 256, 0, stream>>>(ei, ea, counts, dstb, emb);
    bucket_build_kernel<<<NBUCK, 1024, 0, stream>>>(counts, dstb, emb, rowptr, em);

    const int AGG_BLOCKS = N_NODES / 4;
    const dim3 GEMM_GRID((N_NODES + 63) / 64, 2);

    agg_kernel<64><<<AGG_BLOCKS, 256, 0, stream>>>(x, rowptr, em, agg);
    gemm_bn_relu<64><<<GEMM_GRID, 256, 0, stream>>>(agg, x, rel_w[0], root_w[0], rel_b[0],
                                                    bn_g[0], bn_b[0], bn_m[0], bn_v[0], h_a);
    agg_kernel<128><<<AGG_BLOCKS, 256, 0, stream>>>(h_a, rowptr, em, agg);
    gemm_bn_relu<128><<<GEMM_GRID, 256, 0, stream>>>(agg, h_a, rel_w[1], root_w[1], rel_b[1],
                                                     bn_g[1], bn_b[1], bn_m[1], bn_v[1], h_b);
    agg_kernel<128><<<AGG_BLOCKS, 256, 0, stream>>>(h_b, rowptr, em, agg);
    gemm_bn_relu<128><<<GEMM_GRID, 256, 0, stream>>>(agg, h_b, rel_w[2], root_w[2], rel_b[2],
                                                     bn_g[2], bn_b[2], bn_m[2], bn_v[2], h_a);

    pool_kernel<<<(N_NODES + POOL_NODES - 1) / POOL_NODES, 256, 0, stream>>>(h_a, batch, pooled);
    head_kernel<<<N_GRAPHS, 64, 0, stream>>>(pooled, batch, head_w1, head_b1, head_w2, head_b2, out);
}

// Round 5
// 587.808 us; speedup vs baseline: 2.2835x; 1.3713x over previous
//
#include <hip/hip_runtime.h>

#define N_NODES 100000
#define N_EDGES 1600000
#define F_IN 64
#define HIDDEN 128
#define N_GRAPHS 1024
#define EPS 1e-5f

typedef short short8 __attribute__((ext_vector_type(8)));
typedef float f32x4 __attribute__((ext_vector_type(4)));
typedef unsigned int uint;
typedef unsigned short ushort;

// fp32 -> bf16 round-to-nearest-even (finite values only)
__device__ __forceinline__ ushort f2b(float f) {
    uint x = __float_as_uint(f);
    return (ushort)((x + 0x7fffu + ((x >> 16) & 1u)) >> 16);
}
__device__ __forceinline__ float b2f_lo(uint u) { return __uint_as_float(u << 16); }
__device__ __forceinline__ float b2f_hi(uint u) { return __uint_as_float(u & 0xffff0000u); }

// two-level counting sort parameters
#define NBLK_A 128
#define CHUNK ((N_EDGES + NBLK_A - 1) / NBLK_A)        // 12500
#define BUCK_SHIFT 9                                    // 512-node windows
#define NBUCK ((N_NODES + 511) / 512)                   // 196
#define SCAN_M (NBUCK * NBLK_A)                         // 25088

// ---------------------------------------------------------------------------
// CSR build via two-level counting sort (no global atomics)
// ---------------------------------------------------------------------------

__global__ __launch_bounds__(256) void bin_count_kernel(const int* __restrict__ ei,
                                                        int* __restrict__ counts) {
    __shared__ int cnt[NBUCK];
    int blk = blockIdx.x, t = threadIdx.x;
    for (int i = t; i < NBUCK; i += 256) cnt[i] = 0;
    __syncthreads();
    int e0 = blk * CHUNK, e1 = min(e0 + CHUNK, N_EDGES);
    for (int e = e0 + t; e < e1; e += 256)
        atomicAdd(&cnt[ei[N_EDGES + e] >> BUCK_SHIFT], 1);
    __syncthreads();
    for (int i = t; i < NBUCK; i += 256) counts[i * NBLK_A + blk] = cnt[i];
}

__global__ __launch_bounds__(1024) void scan_counts_kernel(int* __restrict__ counts,
                                                           int* __restrict__ rowptr) {
    __shared__ int tot[1024];
    const int PT = (SCAN_M + 1023) / 1024;  // 25
    int t = threadIdx.x;
    int base = t * PT;
    int local[PT];
    int s = 0;
    #pragma unroll
    for (int i = 0; i < PT; ++i) {
        int idx = base + i;
        int v = (idx < SCAN_M) ? counts[idx] : 0;
        local[i] = s;
        s += v;
    }
    tot[t] = s;
    __syncthreads();
    int v = s;
    for (int off = 1; off < 1024; off <<= 1) {
        int x = (t >= off) ? tot[t - off] : 0;
        __syncthreads();
        tot[t] += x;
        __syncthreads();
    }
    int excl = tot[t] - v;
    #pragma unroll
    for (int i = 0; i < PT; ++i) {
        int idx = base + i;
        if (idx < SCAN_M) counts[idx] = excl + local[i];
    }
    if (t == 0) rowptr[N_NODES] = N_EDGES;
}

__global__ __launch_bounds__(256) void bin_scatter_kernel(const int* __restrict__ ei,
                                                          const float* __restrict__ ea,
                                                          const int* __restrict__ counts,
                                                          int* __restrict__ dstb,
                                                          int2* __restrict__ emb) {
    __shared__ int cur[NBUCK];
    int blk = blockIdx.x, t = threadIdx.x;
    for (int i = t; i < NBUCK; i += 256) cur[i] = counts[i * NBLK_A + blk];
    __syncthreads();
    int e0 = blk * CHUNK, e1 = min(e0 + CHUNK, N_EDGES);
    for (int e = e0 + t; e < e1; e += 256) {
        int s = ei[e], d = ei[N_EDGES + e];
        float w = ea[e];
        int p = atomicAdd(&cur[d >> BUCK_SHIFT], 1);
        dstb[p] = d;
        emb[p] = make_int2(s, __float_as_int(w));
    }
}

__global__ __launch_bounds__(1024) void bucket_build_kernel(const int* __restrict__ counts,
                                                            const int* __restrict__ dstb,
                                                            const int2* __restrict__ emb,
                                                            int* __restrict__ rowptr,
                                                            int2* __restrict__ em) {
    __shared__ int hist[512];
    __shared__ int cursor[512];
    int b = blockIdx.x, t = threadIdx.x;
    int beg = counts[b * NBLK_A];
    int end = (b + 1 < NBUCK) ? counts[(b + 1) * NBLK_A] : N_EDGES;
    int nbase = b << BUCK_SHIFT;
    int nnodes = min(512, N_NODES - nbase);

    if (t < 512) hist[t] = 0;
    __syncthreads();
    for (int e = beg + t; e < end; e += 1024)
        atomicAdd(&hist[dstb[e] & 511], 1);
    __syncthreads();

    int v = (t < 512) ? hist[t] : 0;
    for (int off = 1; off < 512; off <<= 1) {
        int x = (t < 512 && t >= off) ? hist[t - off] : 0;
        __syncthreads();
        if (t < 512) hist[t] += x;
        __syncthreads();
    }
    if (t < 512) {
        int excl = hist[t] - v;
        cursor[t] = beg + excl;
        if (t < nnodes) rowptr[nbase + t] = beg + excl;
    }
    __syncthreads();

    for (int e = beg + t; e < end; e += 1024) {
        int d = dstb[e];
        int2 m = emb[e];
        int p = atomicAdd(&cursor[d & 511], 1);
        em[p] = m;
    }
}

// ---------------------------------------------------------------------------
// x -> bf16 conversion
// ---------------------------------------------------------------------------

__global__ __launch_bounds__(256) void cvt_x_kernel(const float* __restrict__ x,
                                                    ushort* __restrict__ xb) {
    int i = blockIdx.x * 256 + threadIdx.x;  // over N*64/2
    if (i < N_NODES * 32) {
        float2 v = ((const float2*)x)[i];
        ((uint*)xb)[i] = (uint)f2b(v.x) | ((uint)f2b(v.y) << 16);
    }
}

// ---------------------------------------------------------------------------
// Aggregation (bf16 rows): one wave per node; F=128 -> uint (2 bf16)/lane
// (256B row transaction), F=64 -> ushort/lane. fp32 accum, bf16 store.
// 4-edge unroll for 4 gathers in flight.
// ---------------------------------------------------------------------------

template <int F>
__global__ __launch_bounds__(256) void agg_kernel(const ushort* __restrict__ h,
                                                  const int* __restrict__ rowptr,
                                                  const int2* __restrict__ em,
                                                  ushort* __restrict__ agg) {
    int node = blockIdx.x * 4 + (threadIdx.x >> 6);
    int lane = threadIdx.x & 63;
    int beg = rowptr[node], end = rowptr[node + 1];
    int e = beg;
    if (F == 128) {
        const uint* hp = (const uint*)h;
        float l0 = 0, l1 = 0, l2 = 0, l3 = 0, h0 = 0, h1 = 0, h2 = 0, h3 = 0;
        for (; e + 4 <= end; e += 4) {
            int2 m0 = em[e], m1 = em[e + 1], m2 = em[e + 2], m3 = em[e + 3];
            uint u0 = hp[(size_t)m0.x * 64 + lane];
            uint u1 = hp[(size_t)m1.x * 64 + lane];
            uint u2 = hp[(size_t)m2.x * 64 + lane];
            uint u3 = hp[(size_t)m3.x * 64 + lane];
            float w0 = __int_as_float(m0.y), w1 = __int_as_float(m1.y);
            float w2 = __int_as_float(m2.y), w3 = __int_as_float(m3.y);
            l0 = fmaf(b2f_lo(u0), w0, l0); h0 = fmaf(b2f_hi(u0), w0, h0);
            l1 = fmaf(b2f_lo(u1), w1, l1); h1 = fmaf(b2f_hi(u1), w1, h1);
            l2 = fmaf(b2f_lo(u2), w2, l2); h2 = fmaf(b2f_hi(u2), w2, h2);
            l3 = fmaf(b2f_lo(u3), w3, l3); h3 = fmaf(b2f_hi(u3), w3, h3);
        }
        for (; e < end; ++e) {
            int2 m = em[e];
            float w = __int_as_float(m.y);
            uint u = hp[(size_t)m.x * 64 + lane];
            l0 = fmaf(b2f_lo(u), w, l0); h0 = fmaf(b2f_hi(u), w, h0);
        }
        float lo = (l0 + l1) + (l2 + l3);
        float hi = (h0 + h1) + (h2 + h3);
        ((uint*)agg)[(size_t)node * 64 + lane] = (uint)f2b(lo) | ((uint)f2b(hi) << 16);
    } else {
        float a0 = 0, a1 = 0, a2 = 0, a3 = 0;
        for (; e + 4 <= end; e += 4) {
            int2 m0 = em[e], m1 = em[e + 1], m2 = em[e + 2], m3 = em[e + 3];
            uint u0 = h[(size_t)m0.x * 64 + lane];
            uint u1 = h[(size_t)m1.x * 64 + lane];
            uint u2 = h[(size_t)m2.x * 64 + lane];
            uint u3 = h[(size_t)m3.x * 64 + lane];
            a0 = fmaf(b2f_lo(u0), __int_as_float(m0.y), a0);
            a1 = fmaf(b2f_lo(u1), __int_as_float(m1.y), a1);
            a2 = fmaf(b2f_lo(u2), __int_as_float(m2.y), a2);
            a3 = fmaf(b2f_lo(u3), __int_as_float(m3.y), a3);
        }
        for (; e < end; ++e) {
            int2 m = em[e];
            uint u = h[(size_t)m.x * 64 + lane];
            a0 = fmaf(b2f_lo(u), __int_as_float(m.y), a0);
        }
        agg[(size_t)node * 64 + lane] = f2b((a0 + a1) + (a2 + a3));
    }
}

// ---------------------------------------------------------------------------
// MFMA GEMM + bias + BN + ReLU, bf16 inputs, fp32 accum, bf16 out.
// C[r][c] = relu(BN( [A0|A1][r,:] @ [W0;W1][:,c] + bias[c] ))   K = 2F
// Block: 256 thr = 4 waves, 64 rows x 128 cols. Whole W panel in LDS,
// transposed [c][k] (+8 pad), loaded once. A streamed from global.
// mfma_f32_16x16x32_bf16: A[m=lane&15][k=quad*8+j]; C/D col=lane&15,
// row=quad*4+reg (HW-verified mappings).
// ---------------------------------------------------------------------------

template <int F>
__global__ __launch_bounds__(256, 2) void gemm_mfma(const ushort* __restrict__ A0,  // agg bf16, stride F
                                                    const ushort* __restrict__ A1,  // h bf16,  stride F
                                                    const float* __restrict__ W0,   // (F,128) fp32
                                                    const float* __restrict__ W1,   // (F,128) fp32
                                                    const float* __restrict__ bias,
                                                    const float* __restrict__ bng,
                                                    const float* __restrict__ bnb,
                                                    const float* __restrict__ bnm,
                                                    const float* __restrict__ bnv,
                                                    ushort* __restrict__ out) {     // stride 128 bf16
    constexpr int K = 2 * F;
    constexpr int LDW = K + 8;                 // pad: 2-way LDS aliasing only (free)
    __shared__ ushort Wl[128 * LDW];

    int t = threadIdx.x;
    // fill W panel transposed: Wl[c][k] <- W(k, c), bf16, pairs of k per thread
    for (int idx = t; idx < (K / 2) * 128; idx += 256) {
        int k2 = (idx >> 7) * 2;
        int c  = idx & 127;
        float f0 = (k2 < F) ? W0[k2 * 128 + c] : W1[(k2 - F) * 128 + c];
        float f1 = (k2 + 1 < F) ? W0[(k2 + 1) * 128 + c] : W1[(k2 + 1 - F) * 128 + c];
        *(uint*)&Wl[c * LDW + k2] = (uint)f2b(f0) | ((uint)f2b(f1) << 16);
    }
    __syncthreads();

    int wave = t >> 6, lane = t & 63;
    int m = lane & 15, quad = lane >> 4;
    int arow = blockIdx.x * 64 + wave * 16 + m;     // row this lane's A frag covers
    bool avalid = arow < N_NODES;

    f32x4 acc[8];
    #pragma unroll
    for (int i = 0; i < 8; ++i) acc[i] = (f32x4)(0.f);

    for (int kc = 0; kc < K; kc += 32) {
        int k0 = kc + quad * 8;  // frag never straddles the F boundary (F%32==0)
        short8 a = {};
        if (avalid) {
            const ushort* src = (k0 < F) ? (A0 + (size_t)arow * F + k0)
                                         : (A1 + (size_t)arow * F + (k0 - F));
            a = *(const short8*)src;
        }
        #pragma unroll
        for (int ct = 0; ct < 8; ++ct) {
            short8 b = *(const short8*)&Wl[(ct * 16 + m) * LDW + k0];
            acc[ct] = __builtin_amdgcn_mfma_f32_16x16x32_bf16(a, b, acc[ct], 0, 0, 0);
        }
    }

    // epilogue: bias + BN + relu -> bf16
    int rbase = blockIdx.x * 64 + wave * 16 + quad * 4;
    #pragma unroll
    for (int ct = 0; ct < 8; ++ct) {
        int c = ct * 16 + m;
        float sc = bng[c] * rsqrtf(bnv[c] + EPS);
        float sh = bnb[c] - bnm[c] * sc;
        float bi = bias[c];
        #pragma unroll
        for (int reg = 0; reg < 4; ++reg) {
            int r = rbase + reg;
            if (r < N_NODES) {
                float v = fmaxf(fmaf(acc[ct][reg] + bi, sc, sh), 0.f);
                out[(size_t)r * 128 + c] = f2b(v);
            }
        }
    }
}

// ---------------------------------------------------------------------------
// Pooling: sorted batch -> run-length accumulate (bf16 in, fp32 atomics out)
// ---------------------------------------------------------------------------

#define POOL_NODES 64
__global__ __launch_bounds__(256) void pool_kernel(const ushort* __restrict__ h,
                                                   const int* __restrict__ batch,
                                                   float* __restrict__ pooled) {
    __shared__ int gb[POOL_NODES];
    int b = blockIdx.x, t = threadIdx.x;
    int n0 = b * POOL_NODES;
    if (t < POOL_NODES) {
        int n = n0 + t;
        gb[t] = (n < N_NODES) ? batch[n] : -1;
    }
    __syncthreads();
    int f = t & 127;
    int half = t >> 7;
    float acc = 0.f;
    int gcur = -1;
    for (int i = half; i < POOL_NODES; i += 2) {
        int n = n0 + i;
        if (n >= N_NODES) break;
        int g = gb[i];
        if (g != gcur) {
            if (gcur >= 0) atomicAdd(&pooled[(size_t)gcur * 128 + f], acc);
            gcur = g;
            acc = 0.f;
        }
        acc += b2f_lo((uint)h[(size_t)n * 128 + f]);
    }
    if (gcur >= 0) atomicAdd(&pooled[(size_t)gcur * 128 + f], acc);
}

// ---------------------------------------------------------------------------
// Head: counts via binary search on sorted batch, one wave per graph
// ---------------------------------------------------------------------------

__global__ __launch_bounds__(64) void head_kernel(const float* __restrict__ pooled,
                                                  const int* __restrict__ batch,
                                                  const float* __restrict__ w1,
                                                  const float* __restrict__ b1,
                                                  const float* __restrict__ w2,
                                                  const float* __restrict__ b2,
                                                  float* __restrict__ out) {
    int g = blockIdx.x;
    int j = threadIdx.x;
    int lo = 0, hi = N_NODES;
    while (lo < hi) { int m = (lo + hi) >> 1; if (batch[m] <  g) lo = m + 1; else hi = m; }
    int start = lo;
    lo = 0; hi = N_NODES;
    while (lo < hi) { int m = (lo + hi) >> 1; if (batch[m] <= g) lo = m + 1; else hi = m; }
    float inv = 1.0f / fmaxf((float)(lo - start), 1.0f);

    float acc = b1[j];
    #pragma unroll 4
    for (int k = 0; k < 128; ++k)
        acc = fmaf(pooled[(size_t)g * 128 + k] * inv, w1[k * 64 + j], acc);
    float prod = fmaxf(acc, 0.f) * w2[j];
    #pragma unroll
    for (int off = 32; off > 0; off >>= 1)
        prod += __shfl_down(prod, off);
    if (j == 0) out[g] = prod + b2[0];
}

// ---------------------------------------------------------------------------

extern "C" void kernel_launch(void* const* d_in, const int* in_sizes, int n_in,
                              void* d_out, int out_size, void* d_ws, size_t ws_size,
                              hipStream_t stream) {
    const float* x     = (const float*)d_in[0];
    const int*   ei    = (const int*)d_in[1];
    const float* ea    = (const float*)d_in[2];
    const int*   batch = (const int*)d_in[3];
    const float* rel_w[3]  = {(const float*)d_in[4],  (const float*)d_in[11], (const float*)d_in[18]};
    const float* rel_b[3]  = {(const float*)d_in[5],  (const float*)d_in[12], (const float*)d_in[19]};
    const float* root_w[3] = {(const float*)d_in[6],  (const float*)d_in[13], (const float*)d_in[20]};
    const float* bn_g[3]   = {(const float*)d_in[7],  (const float*)d_in[14], (const float*)d_in[21]};
    const float* bn_b[3]   = {(const float*)d_in[8],  (const float*)d_in[15], (const float*)d_in[22]};
    const float* bn_m[3]   = {(const float*)d_in[9],  (const float*)d_in[16], (const float*)d_in[23]};
    const float* bn_v[3]   = {(const float*)d_in[10], (const float*)d_in[17], (const float*)d_in[24]};
    const float* head_w1 = (const float*)d_in[25];
    const float* head_b1 = (const float*)d_in[26];
    const float* head_w2 = (const float*)d_in[27];
    const float* head_b2 = (const float*)d_in[28];
    float* out = (float*)d_out;

    // workspace layout (~104 MB, under prior 168 MB envelope)
    char* ws = (char*)d_ws;
    int*    rowptr = (int*)(ws + 0);              // N_NODES+1 ints
    int*    counts = (int*)(ws + 401408);         // SCAN_M ints
    int2*   em     = (int2*)(ws + 524288);        // E int2 (src, ew bits)
    ushort* xb     = (ushort*)(ws + 13631488);    // N*64 bf16
    ushort* h_a    = (ushort*)(ws + 26431488);    // N*128 bf16
    ushort* h_b    = (ushort*)(ws + 52031488);    // N*128 bf16
    ushort* aggb   = (ushort*)(ws + 77631488);    // N*128 bf16 (layer0 uses N*64)
    float*  pooled = (float*)(ws + 103231488);    // 1024*128 fp32
    // sort scratch aliases aggb region (dead until first agg)
    int*    dstb = (int*)(ws + 77631488);         // E ints
    int2*   emb  = (int2*)(ws + 84031488);        // E int2

    hipMemsetAsync(pooled, 0, N_GRAPHS * HIDDEN * sizeof(float), stream);

    bin_count_kernel<<<NBLK_A, 256, 0, stream>>>(ei, counts);
    scan_counts_kernel<<<1, 1024, 0, stream>>>(counts, rowptr);
    bin_scatter_kernel<<<NBLK_A, 256, 0, stream>>>(ei, ea, counts, dstb, emb);
    bucket_build_kernel<<<NBUCK, 1024, 0, stream>>>(counts, dstb, emb, rowptr, em);
    cvt_x_kernel<<<(N_NODES * 32 + 255) / 256, 256, 0, stream>>>(x, xb);

    const int AGG_BLOCKS = N_NODES / 4;
    const int GEMM_BLOCKS = (N_NODES + 63) / 64;

    agg_kernel<64><<<AGG_BLOCKS, 256, 0, stream>>>(xb, rowptr, em, aggb);
    gemm_mfma<64><<<GEMM_BLOCKS, 256, 0, stream>>>(aggb, xb, rel_w[0], root_w[0], rel_b[0],
                                                   bn_g[0], bn_b[0], bn_m[0], bn_v[0], h_a);
    agg_kernel<128><<<AGG_BLOCKS, 256, 0, stream>>>(h_a, rowptr, em, aggb);
    gemm_mfma<128><<<GEMM_BLOCKS, 256, 0, stream>>>(aggb, h_a, rel_w[1], root_w[1], rel_b[1],
                                                    bn_g[1], bn_b[1], bn_m[1], bn_v[1], h_b);
    agg_kernel<128><<<AGG_BLOCKS, 256, 0, stream>>>(h_b, rowptr, em, aggb);
    gemm_mfma<128><<<GEMM_BLOCKS, 256, 0, stream>>>(aggb, h_b, rel_w[2], root_w[2], rel_b[2],
                                                    bn_g[2], bn_b[2], bn_m[2], bn_v[2], h_a);

    pool_kernel<<<(N_NODES + POOL_NODES - 1) / POOL_NODES, 256, 0, stream>>>(h_a, batch, pooled);
    head_kernel<<<N_GRAPHS, 64, 0, stream>>>(pooled, batch, head_w1, head_b1, head_w2, head_b2, out);
}

// Round 6
// 587.232 us; speedup vs baseline: 2.2858x; 1.0010x over previous
//
#include <hip/hip_runtime.h>

#define N_NODES 100000
#define N_EDGES 1600000
#define F_IN 64
#define HIDDEN 128
#define N_GRAPHS 1024
#define EPS 1e-5f

typedef short short8 __attribute__((ext_vector_type(8)));
typedef float f32x4 __attribute__((ext_vector_type(4)));
typedef unsigned int uint;
typedef unsigned short ushort;

// fp32 -> bf16 round-to-nearest-even (finite values only)
__device__ __forceinline__ ushort f2b(float f) {
    uint x = __float_as_uint(f);
    return (ushort)((x + 0x7fffu + ((x >> 16) & 1u)) >> 16);
}
__device__ __forceinline__ float b2f_lo(uint u) { return __uint_as_float(u << 16); }
__device__ __forceinline__ float b2f_hi(uint u) { return __uint_as_float(u & 0xffff0000u); }

// two-level counting sort parameters
#define NBLK_A 128
#define CHUNK ((N_EDGES + NBLK_A - 1) / NBLK_A)        // 12500
#define BUCK_SHIFT 9                                    // 512-node windows
#define NBUCK ((N_NODES + 511) / 512)                   // 196
#define SCAN_M (NBUCK * NBLK_A)                         // 25088

// ---------------------------------------------------------------------------
// CSR build via two-level counting sort (no global atomics)
// ---------------------------------------------------------------------------

__global__ __launch_bounds__(256) void bin_count_kernel(const int* __restrict__ ei,
                                                        int* __restrict__ counts) {
    __shared__ int cnt[NBUCK];
    int blk = blockIdx.x, t = threadIdx.x;
    for (int i = t; i < NBUCK; i += 256) cnt[i] = 0;
    __syncthreads();
    int e0 = blk * CHUNK, e1 = min(e0 + CHUNK, N_EDGES);
    for (int e = e0 + t; e < e1; e += 256)
        atomicAdd(&cnt[ei[N_EDGES + e] >> BUCK_SHIFT], 1);
    __syncthreads();
    for (int i = t; i < NBUCK; i += 256) counts[i * NBLK_A + blk] = cnt[i];
}

__global__ __launch_bounds__(1024) void scan_counts_kernel(int* __restrict__ counts,
                                                           int* __restrict__ rowptr) {
    __shared__ int tot[1024];
    const int PT = (SCAN_M + 1023) / 1024;  // 25
    int t = threadIdx.x;
    int base = t * PT;
    int local[PT];
    int s = 0;
    #pragma unroll
    for (int i = 0; i < PT; ++i) {
        int idx = base + i;
        int v = (idx < SCAN_M) ? counts[idx] : 0;
        local[i] = s;
        s += v;
    }
    tot[t] = s;
    __syncthreads();
    int v = s;
    for (int off = 1; off < 1024; off <<= 1) {
        int x = (t >= off) ? tot[t - off] : 0;
        __syncthreads();
        tot[t] += x;
        __syncthreads();
    }
    int excl = tot[t] - v;
    #pragma unroll
    for (int i = 0; i < PT; ++i) {
        int idx = base + i;
        if (idx < SCAN_M) counts[idx] = excl + local[i];
    }
    if (t == 0) rowptr[N_NODES] = N_EDGES;
}

__global__ __launch_bounds__(256) void bin_scatter_kernel(const int* __restrict__ ei,
                                                          const float* __restrict__ ea,
                                                          const int* __restrict__ counts,
                                                          int* __restrict__ dstb,
                                                          int2* __restrict__ emb) {
    __shared__ int cur[NBUCK];
    int blk = blockIdx.x, t = threadIdx.x;
    for (int i = t; i < NBUCK; i += 256) cur[i] = counts[i * NBLK_A + blk];
    __syncthreads();
    int e0 = blk * CHUNK, e1 = min(e0 + CHUNK, N_EDGES);
    for (int e = e0 + t; e < e1; e += 256) {
        int s = ei[e], d = ei[N_EDGES + e];
        float w = ea[e];
        int p = atomicAdd(&cur[d >> BUCK_SHIFT], 1);
        dstb[p] = d;
        emb[p] = make_int2(s, __float_as_int(w));
    }
}

__global__ __launch_bounds__(1024) void bucket_build_kernel(const int* __restrict__ counts,
                                                            const int* __restrict__ dstb,
                                                            const int2* __restrict__ emb,
                                                            int* __restrict__ rowptr,
                                                            int2* __restrict__ em) {
    __shared__ int hist[512];
    __shared__ int cursor[512];
    int b = blockIdx.x, t = threadIdx.x;
    int beg = counts[b * NBLK_A];
    int end = (b + 1 < NBUCK) ? counts[(b + 1) * NBLK_A] : N_EDGES;
    int nbase = b << BUCK_SHIFT;
    int nnodes = min(512, N_NODES - nbase);

    if (t < 512) hist[t] = 0;
    __syncthreads();
    for (int e = beg + t; e < end; e += 1024)
        atomicAdd(&hist[dstb[e] & 511], 1);
    __syncthreads();

    int v = (t < 512) ? hist[t] : 0;
    for (int off = 1; off < 512; off <<= 1) {
        int x = (t < 512 && t >= off) ? hist[t - off] : 0;
        __syncthreads();
        if (t < 512) hist[t] += x;
        __syncthreads();
    }
    if (t < 512) {
        int excl = hist[t] - v;
        cursor[t] = beg + excl;
        if (t < nnodes) rowptr[nbase + t] = beg + excl;
    }
    __syncthreads();

    for (int e = beg + t; e < end; e += 1024) {
        int d = dstb[e];
        int2 m = emb[e];
        int p = atomicAdd(&cursor[d & 511], 1);
        em[p] = m;
    }
}

// ---------------------------------------------------------------------------
// Conversions: x -> bf16; W panels -> bf16 transposed [c][k] (once per call)
// ---------------------------------------------------------------------------

__global__ __launch_bounds__(256) void cvt_x_kernel(const float* __restrict__ x,
                                                    ushort* __restrict__ xb) {
    int i = blockIdx.x * 256 + threadIdx.x;  // over N*64/2
    if (i < N_NODES * 32) {
        float2 v = ((const float2*)x)[i];
        ((uint*)xb)[i] = (uint)f2b(v.x) | ((uint)f2b(v.y) << 16);
    }
}

// Wb[c][k] = bf16( k<F ? W0(k,c) : W1(k-F,c) ), c in [0,128), k in [0,2F)
__global__ __launch_bounds__(256) void cvt_w_kernel(const float* __restrict__ W0,
                                                    const float* __restrict__ W1,
                                                    int F, ushort* __restrict__ Wb) {
    int K = 2 * F;
    int idx = blockIdx.x * 256 + threadIdx.x;  // over 128*K/2 uints
    if (idx >= 64 * K) return;
    int c  = idx / (K / 2);
    int k2 = (idx % (K / 2)) * 2;
    float f0 = (k2 < F) ? W0[k2 * 128 + c] : W1[(k2 - F) * 128 + c];
    float f1 = (k2 + 1 < F) ? W0[(k2 + 1) * 128 + c] : W1[(k2 + 1 - F) * 128 + c];
    ((uint*)Wb)[idx] = (uint)f2b(f0) | ((uint)f2b(f1) << 16);
}

// ---------------------------------------------------------------------------
// Aggregation (bf16 rows): one wave per node; 8-edge unroll -> 8 gathers in
// flight per wave. fp32 accum, bf16 store.
// ---------------------------------------------------------------------------

template <int F>
__global__ __launch_bounds__(256) void agg_kernel(const ushort* __restrict__ h,
                                                  const int* __restrict__ rowptr,
                                                  const int2* __restrict__ em,
                                                  ushort* __restrict__ agg) {
    int node = blockIdx.x * 4 + (threadIdx.x >> 6);
    int lane = threadIdx.x & 63;
    int beg = rowptr[node], end = rowptr[node + 1];
    int e = beg;
    if (F == 128) {
        const uint* hp = (const uint*)h;
        float lo[8] = {}, hi[8] = {};
        for (; e + 8 <= end; e += 8) {
            uint u[8]; float w[8];
            #pragma unroll
            for (int j = 0; j < 8; ++j) {
                int2 m = em[e + j];
                u[j] = hp[(size_t)m.x * 64 + lane];
                w[j] = __int_as_float(m.y);
            }
            #pragma unroll
            for (int j = 0; j < 8; ++j) {
                lo[j] = fmaf(b2f_lo(u[j]), w[j], lo[j]);
                hi[j] = fmaf(b2f_hi(u[j]), w[j], hi[j]);
            }
        }
        for (; e < end; ++e) {
            int2 m = em[e];
            float w = __int_as_float(m.y);
            uint u = hp[(size_t)m.x * 64 + lane];
            lo[0] = fmaf(b2f_lo(u), w, lo[0]);
            hi[0] = fmaf(b2f_hi(u), w, hi[0]);
        }
        float l = ((lo[0] + lo[1]) + (lo[2] + lo[3])) + ((lo[4] + lo[5]) + (lo[6] + lo[7]));
        float hh = ((hi[0] + hi[1]) + (hi[2] + hi[3])) + ((hi[4] + hi[5]) + (hi[6] + hi[7]));
        ((uint*)agg)[(size_t)node * 64 + lane] = (uint)f2b(l) | ((uint)f2b(hh) << 16);
    } else {
        float a[8] = {};
        for (; e + 8 <= end; e += 8) {
            uint u[8]; float w[8];
            #pragma unroll
            for (int j = 0; j < 8; ++j) {
                int2 m = em[e + j];
                u[j] = h[(size_t)m.x * 64 + lane];
                w[j] = __int_as_float(m.y);
            }
            #pragma unroll
            for (int j = 0; j < 8; ++j)
                a[j] = fmaf(b2f_lo(u[j]), w[j], a[j]);
        }
        for (; e < end; ++e) {
            int2 m = em[e];
            uint u = h[(size_t)m.x * 64 + lane];
            a[0] = fmaf(b2f_lo(u), __int_as_float(m.y), a[0]);
        }
        float s = ((a[0] + a[1]) + (a[2] + a[3])) + ((a[4] + a[5]) + (a[6] + a[7]));
        agg[(size_t)node * 64 + lane] = f2b(s);
    }
}

// ---------------------------------------------------------------------------
// MFMA GEMM + bias + BN + ReLU. bf16 in, fp32 accum, bf16 out. K = 2F.
// Block: 256 thr = 4 waves, 128 rows x 128 cols; 32 rows/wave (2 m-tiles).
// W panel (pre-converted bf16, [c][k]) copied once to LDS (+8 pad).
// A streamed from global with 1-deep register prefetch across the K-loop.
// mfma_f32_16x16x32_bf16: A[m=lane&15][k=quad*8+j]; C/D col=lane&15,
// row=quad*4+reg (HW-verified mappings).
// ---------------------------------------------------------------------------

template <int F>
__global__ __launch_bounds__(256, 2) void gemm_mfma(const ushort* __restrict__ A0,  // agg bf16, stride F
                                                    const ushort* __restrict__ A1,  // h bf16,  stride F
                                                    const ushort* __restrict__ Wb,  // [128][K] bf16
                                                    const float* __restrict__ bias,
                                                    const float* __restrict__ bng,
                                                    const float* __restrict__ bnb,
                                                    const float* __restrict__ bnm,
                                                    const float* __restrict__ bnv,
                                                    ushort* __restrict__ out) {     // stride 128 bf16
    constexpr int K = 2 * F;
    constexpr int LDW = K + 8;
    __shared__ ushort Wl[128 * LDW];

    int t = threadIdx.x;
    // straight 16B-chunk copy of the bf16 W panel into padded LDS
    for (int idx = t; idx < 128 * (K / 8); idx += 256) {
        int c  = idx / (K / 8);
        int k8 = (idx % (K / 8)) * 8;
        *(short8*)&Wl[c * LDW + k8] = *(const short8*)&Wb[c * K + k8];
    }
    __syncthreads();

    int wave = t >> 6, lane = t & 63;
    int m = lane & 15, quad = lane >> 4;
    int r0 = blockIdx.x * 128 + wave * 32 + m;
    int r1 = r0 + 16;

    f32x4 acc0[8], acc1[8];
    #pragma unroll
    for (int i = 0; i < 8; ++i) { acc0[i] = (f32x4)(0.f); acc1[i] = (f32x4)(0.f); }

    auto loadA = [&](int row, int k0) -> short8 {
        short8 v = {};
        if (row < N_NODES)
            v = (k0 < F) ? *(const short8*)(A0 + (size_t)row * F + k0)
                         : *(const short8*)(A1 + (size_t)row * F + (k0 - F));
        return v;
    };

    short8 a0 = loadA(r0, quad * 8);
    short8 a1 = loadA(r1, quad * 8);
    for (int kc = 0; kc < K; kc += 32) {
        int k0 = kc + quad * 8;
        short8 na0 = {}, na1 = {};
        if (kc + 32 < K) {
            na0 = loadA(r0, k0 + 32);
            na1 = loadA(r1, k0 + 32);
        }
        #pragma unroll
        for (int ct = 0; ct < 8; ++ct) {
            short8 b = *(const short8*)&Wl[(ct * 16 + m) * LDW + k0];
            acc0[ct] = __builtin_amdgcn_mfma_f32_16x16x32_bf16(a0, b, acc0[ct], 0, 0, 0);
            acc1[ct] = __builtin_amdgcn_mfma_f32_16x16x32_bf16(a1, b, acc1[ct], 0, 0, 0);
        }
        a0 = na0; a1 = na1;
    }

    // epilogue: bias + BN + relu -> bf16, both row tiles
    int rb0 = blockIdx.x * 128 + wave * 32 + quad * 4;
    #pragma unroll
    for (int ct = 0; ct < 8; ++ct) {
        int c = ct * 16 + m;
        float sc = bng[c] * rsqrtf(bnv[c] + EPS);
        float sh = bnb[c] - bnm[c] * sc;
        float bi = bias[c];
        #pragma unroll
        for (int reg = 0; reg < 4; ++reg) {
            int r = rb0 + reg;
            if (r < N_NODES) {
                float v = fmaxf(fmaf(acc0[ct][reg] + bi, sc, sh), 0.f);
                out[(size_t)r * 128 + c] = f2b(v);
            }
            int r2 = rb0 + 16 + reg;
            if (r2 < N_NODES) {
                float v = fmaxf(fmaf(acc1[ct][reg] + bi, sc, sh), 0.f);
                out[(size_t)r2 * 128 + c] = f2b(v);
            }
        }
    }
}

// ---------------------------------------------------------------------------
// Pooling: sorted batch -> run-length accumulate (bf16 in, fp32 atomics out)
// ---------------------------------------------------------------------------

#define POOL_NODES 64
__global__ __launch_bounds__(256) void pool_kernel(const ushort* __restrict__ h,
                                                   const int* __restrict__ batch,
                                                   float* __restrict__ pooled) {
    __shared__ int gb[POOL_NODES];
    int b = blockIdx.x, t = threadIdx.x;
    int n0 = b * POOL_NODES;
    if (t < POOL_NODES) {
        int n = n0 + t;
        gb[t] = (n < N_NODES) ? batch[n] : -1;
    }
    __syncthreads();
    int f = t & 127;
    int half = t >> 7;
    float acc = 0.f;
    int gcur = -1;
    for (int i = half; i < POOL_NODES; i += 2) {
        int n = n0 + i;
        if (n >= N_NODES) break;
        int g = gb[i];
        if (g != gcur) {
            if (gcur >= 0) atomicAdd(&pooled[(size_t)gcur * 128 + f], acc);
            gcur = g;
            acc = 0.f;
        }
        acc += b2f_lo((uint)h[(size_t)n * 128 + f]);
    }
    if (gcur >= 0) atomicAdd(&pooled[(size_t)gcur * 128 + f], acc);
}

// ---------------------------------------------------------------------------
// Head: counts via binary search on sorted batch, one wave per graph
// ---------------------------------------------------------------------------

__global__ __launch_bounds__(64) void head_kernel(const float* __restrict__ pooled,
                                                  const int* __restrict__ batch,
                                                  const float* __restrict__ w1,
                                                  const float* __restrict__ b1,
                                                  const float* __restrict__ w2,
                                                  const float* __restrict__ b2,
                                                  float* __restrict__ out) {
    int g = blockIdx.x;
    int j = threadIdx.x;
    int lo = 0, hi = N_NODES;
    while (lo < hi) { int m = (lo + hi) >> 1; if (batch[m] <  g) lo = m + 1; else hi = m; }
    int start = lo;
    lo = 0; hi = N_NODES;
    while (lo < hi) { int m = (lo + hi) >> 1; if (batch[m] <= g) lo = m + 1; else hi = m; }
    float inv = 1.0f / fmaxf((float)(lo - start), 1.0f);

    float acc = b1[j];
    #pragma unroll 4
    for (int k = 0; k < 128; ++k)
        acc = fmaf(pooled[(size_t)g * 128 + k] * inv, w1[k * 64 + j], acc);
    float prod = fmaxf(acc, 0.f) * w2[j];
    #pragma unroll
    for (int off = 32; off > 0; off >>= 1)
        prod += __shfl_down(prod, off);
    if (j == 0) out[g] = prod + b2[0];
}

// ---------------------------------------------------------------------------

extern "C" void kernel_launch(void* const* d_in, const int* in_sizes, int n_in,
                              void* d_out, int out_size, void* d_ws, size_t ws_size,
                              hipStream_t stream) {
    const float* x     = (const float*)d_in[0];
    const int*   ei    = (const int*)d_in[1];
    const float* ea    = (const float*)d_in[2];
    const int*   batch = (const int*)d_in[3];
    const float* rel_w[3]  = {(const float*)d_in[4],  (const float*)d_in[11], (const float*)d_in[18]};
    const float* rel_b[3]  = {(const float*)d_in[5],  (const float*)d_in[12], (const float*)d_in[19]};
    const float* root_w[3] = {(const float*)d_in[6],  (const float*)d_in[13], (const float*)d_in[20]};
    const float* bn_g[3]   = {(const float*)d_in[7],  (const float*)d_in[14], (const float*)d_in[21]};
    const float* bn_b[3]   = {(const float*)d_in[8],  (const float*)d_in[15], (const float*)d_in[22]};
    const float* bn_m[3]   = {(const float*)d_in[9],  (const float*)d_in[16], (const float*)d_in[23]};
    const float* bn_v[3]   = {(const float*)d_in[10], (const float*)d_in[17], (const float*)d_in[24]};
    const float* head_w1 = (const float*)d_in[25];
    const float* head_b1 = (const float*)d_in[26];
    const float* head_w2 = (const float*)d_in[27];
    const float* head_b2 = (const float*)d_in[28];
    float* out = (float*)d_out;

    // workspace layout (~104 MB)
    char* ws = (char*)d_ws;
    int*    rowptr = (int*)(ws + 0);              // N_NODES+1 ints
    int*    counts = (int*)(ws + 401408);         // SCAN_M ints
    int2*   em     = (int2*)(ws + 524288);        // E int2 (src, ew bits)
    ushort* xb     = (ushort*)(ws + 13631488);    // N*64 bf16
    ushort* h_a    = (ushort*)(ws + 26431488);    // N*128 bf16
    ushort* h_b    = (ushort*)(ws + 52031488);    // N*128 bf16
    ushort* aggb   = (ushort*)(ws + 77631488);    // N*128 bf16 (layer0 uses N*64)
    float*  pooled = (float*)(ws + 103231488);    // 1024*128 fp32
    ushort* wb     = (ushort*)(ws + 103755776);   // 81920 bf16 (3 W panels)
    // sort scratch aliases aggb region (dead until first agg)
    int*    dstb = (int*)(ws + 77631488);         // E ints
    int2*   emb  = (int2*)(ws + 84031488);        // E int2

    ushort* wb0 = wb;            // 128*128
    ushort* wb1 = wb + 16384;    // 128*256
    ushort* wb2 = wb + 49152;    // 128*256

    hipMemsetAsync(pooled, 0, N_GRAPHS * HIDDEN * sizeof(float), stream);

    bin_count_kernel<<<NBLK_A, 256, 0, stream>>>(ei, counts);
    scan_counts_kernel<<<1, 1024, 0, stream>>>(counts, rowptr);
    bin_scatter_kernel<<<NBLK_A, 256, 0, stream>>>(ei, ea, counts, dstb, emb);
    bucket_build_kernel<<<NBUCK, 1024, 0, stream>>>(counts, dstb, emb, rowptr, em);
    cvt_x_kernel<<<(N_NODES * 32 + 255) / 256, 256, 0, stream>>>(x, xb);
    cvt_w_kernel<<<(64 * 128 + 255) / 256, 256, 0, stream>>>(rel_w[0], root_w[0], 64,  wb0);
    cvt_w_kernel<<<(64 * 256 + 255) / 256, 256, 0, stream>>>(rel_w[1], root_w[1], 128, wb1);
    cvt_w_kernel<<<(64 * 256 + 255) / 256, 256, 0, stream>>>(rel_w[2], root_w[2], 128, wb2);

    const int AGG_BLOCKS  = N_NODES / 4;
    const int GEMM_BLOCKS = (N_NODES + 127) / 128;

    agg_kernel<64><<<AGG_BLOCKS, 256, 0, stream>>>(xb, rowptr, em, aggb);
    gemm_mfma<64><<<GEMM_BLOCKS, 256, 0, stream>>>(aggb, xb, wb0, rel_b[0],
                                                   bn_g[0], bn_b[0], bn_m[0], bn_v[0], h_a);
    agg_kernel<128><<<AGG_BLOCKS, 256, 0, stream>>>(h_a, rowptr, em, aggb);
    gemm_mfma<128><<<GEMM_BLOCKS, 256, 0, stream>>>(aggb, h_a, wb1, rel_b[1],
                                                    bn_g[1], bn_b[1], bn_m[1], bn_v[1], h_b);
    agg_kernel<128><<<AGG_BLOCKS, 256, 0, stream>>>(h_b, rowptr, em, aggb);
    gemm_mfma<128><<<GEMM_BLOCKS, 256, 0, stream>>>(aggb, h_b, wb2, rel_b[2],
                                                    bn_g[2], bn_b[2], bn_m[2], bn_v[2], h_a);

    pool_kernel<<<(N_NODES + POOL_NODES - 1) / POOL_NODES, 256, 0, stream>>>(h_a, batch, pooled);
    head_kernel<<<N_GRAPHS, 64, 0, stream>>>(pooled, batch, head_w1, head_b1, head_w2, head_b2, out);
}

// Round 7
// 527.604 us; speedup vs baseline: 2.5441x; 1.1130x over previous
//
#include <hip/hip_runtime.h>

#define N_NODES 100000
#define N_EDGES 1600000
#define F_IN 64
#define HIDDEN 128
#define N_GRAPHS 1024
#define EPS 1e-5f

typedef short short8 __attribute__((ext_vector_type(8)));
typedef float f32x4 __attribute__((ext_vector_type(4)));
typedef unsigned int uint;
typedef unsigned short ushort;

// fp32 -> bf16 round-to-nearest-even (finite values only)
__device__ __forceinline__ ushort f2b(float f) {
    uint x = __float_as_uint(f);
    return (ushort)((x + 0x7fffu + ((x >> 16) & 1u)) >> 16);
}
__device__ __forceinline__ uint pack2(float a, float b) {
    return (uint)f2b(a) | ((uint)f2b(b) << 16);
}
__device__ __forceinline__ float b2f_lo(uint u) { return __uint_as_float(u << 16); }
__device__ __forceinline__ float b2f_hi(uint u) { return __uint_as_float(u & 0xffff0000u); }

// two-level counting sort parameters
#define NBLK_A 128
#define CHUNK ((N_EDGES + NBLK_A - 1) / NBLK_A)        // 12500
#define BUCK_SHIFT 9                                    // 512-node windows
#define NBUCK ((N_NODES + 511) / 512)                   // 196
#define SCAN_M (NBUCK * NBLK_A)                         // 25088

// ---------------------------------------------------------------------------
// CSR build via two-level counting sort (no global atomics)
// ---------------------------------------------------------------------------

__global__ __launch_bounds__(256) void bin_count_kernel(const int* __restrict__ ei,
                                                        int* __restrict__ counts) {
    __shared__ int cnt[NBUCK];
    int blk = blockIdx.x, t = threadIdx.x;
    for (int i = t; i < NBUCK; i += 256) cnt[i] = 0;
    __syncthreads();
    int e0 = blk * CHUNK, e1 = min(e0 + CHUNK, N_EDGES);
    for (int e = e0 + t; e < e1; e += 256)
        atomicAdd(&cnt[ei[N_EDGES + e] >> BUCK_SHIFT], 1);
    __syncthreads();
    for (int i = t; i < NBUCK; i += 256) counts[i * NBLK_A + blk] = cnt[i];
}

__global__ __launch_bounds__(1024) void scan_counts_kernel(int* __restrict__ counts,
                                                           int* __restrict__ rowptr) {
    __shared__ int tot[1024];
    const int PT = (SCAN_M + 1023) / 1024;  // 25
    int t = threadIdx.x;
    int base = t * PT;
    int local[PT];
    int s = 0;
    #pragma unroll
    for (int i = 0; i < PT; ++i) {
        int idx = base + i;
        int v = (idx < SCAN_M) ? counts[idx] : 0;
        local[i] = s;
        s += v;
    }
    tot[t] = s;
    __syncthreads();
    int v = s;
    for (int off = 1; off < 1024; off <<= 1) {
        int x = (t >= off) ? tot[t - off] : 0;
        __syncthreads();
        tot[t] += x;
        __syncthreads();
    }
    int excl = tot[t] - v;
    #pragma unroll
    for (int i = 0; i < PT; ++i) {
        int idx = base + i;
        if (idx < SCAN_M) counts[idx] = excl + local[i];
    }
    if (t == 0) rowptr[N_NODES] = N_EDGES;
}

__global__ __launch_bounds__(256) void bin_scatter_kernel(const int* __restrict__ ei,
                                                          const float* __restrict__ ea,
                                                          const int* __restrict__ counts,
                                                          int* __restrict__ dstb,
                                                          int2* __restrict__ emb) {
    __shared__ int cur[NBUCK];
    int blk = blockIdx.x, t = threadIdx.x;
    for (int i = t; i < NBUCK; i += 256) cur[i] = counts[i * NBLK_A + blk];
    __syncthreads();
    int e0 = blk * CHUNK, e1 = min(e0 + CHUNK, N_EDGES);
    for (int e = e0 + t; e < e1; e += 256) {
        int s = ei[e], d = ei[N_EDGES + e];
        float w = ea[e];
        int p = atomicAdd(&cur[d >> BUCK_SHIFT], 1);
        dstb[p] = d;
        emb[p] = make_int2(s, __float_as_int(w));
    }
}

__global__ __launch_bounds__(1024) void bucket_build_kernel(const int* __restrict__ counts,
                                                            const int* __restrict__ dstb,
                                                            const int2* __restrict__ emb,
                                                            int* __restrict__ rowptr,
                                                            int2* __restrict__ em) {
    __shared__ int hist[512];
    __shared__ int cursor[512];
    int b = blockIdx.x, t = threadIdx.x;
    int beg = counts[b * NBLK_A];
    int end = (b + 1 < NBUCK) ? counts[(b + 1) * NBLK_A] : N_EDGES;
    int nbase = b << BUCK_SHIFT;
    int nnodes = min(512, N_NODES - nbase);

    if (t < 512) hist[t] = 0;
    __syncthreads();
    for (int e = beg + t; e < end; e += 1024)
        atomicAdd(&hist[dstb[e] & 511], 1);
    __syncthreads();

    int v = (t < 512) ? hist[t] : 0;
    for (int off = 1; off < 512; off <<= 1) {
        int x = (t < 512 && t >= off) ? hist[t - off] : 0;
        __syncthreads();
        if (t < 512) hist[t] += x;
        __syncthreads();
    }
    if (t < 512) {
        int excl = hist[t] - v;
        cursor[t] = beg + excl;
        if (t < nnodes) rowptr[nbase + t] = beg + excl;
    }
    __syncthreads();

    for (int e = beg + t; e < end; e += 1024) {
        int d = dstb[e];
        int2 m = emb[e];
        int p = atomicAdd(&cursor[d & 511], 1);
        em[p] = m;
    }
}

// ---------------------------------------------------------------------------
// Conversions: x -> bf16; W panels -> bf16 transposed [c][k] (once per call)
// ---------------------------------------------------------------------------

__global__ __launch_bounds__(256) void cvt_x_kernel(const float* __restrict__ x,
                                                    ushort* __restrict__ xb) {
    int i = blockIdx.x * 256 + threadIdx.x;  // over N*64/2
    if (i < N_NODES * 32) {
        float2 v = ((const float2*)x)[i];
        ((uint*)xb)[i] = pack2(v.x, v.y);
    }
}

// Wb[c][k] = bf16( k<F ? W0(k,c) : W1(k-F,c) ), c in [0,128), k in [0,2F)
__global__ __launch_bounds__(256) void cvt_w_kernel(const float* __restrict__ W0,
                                                    const float* __restrict__ W1,
                                                    int F, ushort* __restrict__ Wb) {
    int K = 2 * F;
    int idx = blockIdx.x * 256 + threadIdx.x;  // over 128*K/2 uints
    if (idx >= 64 * K) return;
    int c  = idx / (K / 2);
    int k2 = (idx % (K / 2)) * 2;
    float f0 = (k2 < F) ? W0[k2 * 128 + c] : W1[(k2 - F) * 128 + c];
    float f1 = (k2 + 1 < F) ? W0[(k2 + 1) * 128 + c] : W1[(k2 + 1 - F) * 128 + c];
    ((uint*)Wb)[idx] = pack2(f0, f1);
}

// ---------------------------------------------------------------------------
// Aggregation: one wave per node, wave split into 4 x 16-lane groups.
// Group g handles edge e+g; lane slot sl covers a 16B (F=128, uint4) or 8B
// (F=64, uint2) slice of the gathered row -> one wave64 load = 4 rows (1KB).
// 2-deep unroll -> 8 rows in flight. Group partials reduced via shfl_xor.
// ---------------------------------------------------------------------------

template <int F>
__global__ __launch_bounds__(256) void agg_kernel(const ushort* __restrict__ h,
                                                  const int* __restrict__ rowptr,
                                                  const int2* __restrict__ em,
                                                  ushort* __restrict__ agg) {
    int node = blockIdx.x * 4 + (threadIdx.x >> 6);
    int lane = threadIdx.x & 63;
    int g  = lane >> 4;   // edge sub-group 0..3
    int sl = lane & 15;   // slot within row
    int beg = rowptr[node], end = rowptr[node + 1];
    int e = beg;

    if (F == 128) {
        float acc[8] = {};
        for (; e + 8 <= end; e += 8) {
            int2 mA = em[e + g];
            int2 mB = em[e + 4 + g];
            uint4 vA = *(const uint4*)(h + (size_t)mA.x * 128 + sl * 8);
            uint4 vB = *(const uint4*)(h + (size_t)mB.x * 128 + sl * 8);
            float wA = __int_as_float(mA.y), wB = __int_as_float(mB.y);
            acc[0] = fmaf(b2f_lo(vA.x), wA, acc[0]);
            acc[1] = fmaf(b2f_hi(vA.x), wA, acc[1]);
            acc[2] = fmaf(b2f_lo(vA.y), wA, acc[2]);
            acc[3] = fmaf(b2f_hi(vA.y), wA, acc[3]);
            acc[4] = fmaf(b2f_lo(vA.z), wA, acc[4]);
            acc[5] = fmaf(b2f_hi(vA.z), wA, acc[5]);
            acc[6] = fmaf(b2f_lo(vA.w), wA, acc[6]);
            acc[7] = fmaf(b2f_hi(vA.w), wA, acc[7]);
            acc[0] = fmaf(b2f_lo(vB.x), wB, acc[0]);
            acc[1] = fmaf(b2f_hi(vB.x), wB, acc[1]);
            acc[2] = fmaf(b2f_lo(vB.y), wB, acc[2]);
            acc[3] = fmaf(b2f_hi(vB.y), wB, acc[3]);
            acc[4] = fmaf(b2f_lo(vB.z), wB, acc[4]);
            acc[5] = fmaf(b2f_hi(vB.z), wB, acc[5]);
            acc[6] = fmaf(b2f_lo(vB.w), wB, acc[6]);
            acc[7] = fmaf(b2f_hi(vB.w), wB, acc[7]);
        }
        for (; e < end; e += 4) {
            int ej = e + g;
            if (ej < end) {
                int2 m = em[ej];
                uint4 v = *(const uint4*)(h + (size_t)m.x * 128 + sl * 8);
                float w = __int_as_float(m.y);
                acc[0] = fmaf(b2f_lo(v.x), w, acc[0]);
                acc[1] = fmaf(b2f_hi(v.x), w, acc[1]);
                acc[2] = fmaf(b2f_lo(v.y), w, acc[2]);
                acc[3] = fmaf(b2f_hi(v.y), w, acc[3]);
                acc[4] = fmaf(b2f_lo(v.z), w, acc[4]);
                acc[5] = fmaf(b2f_hi(v.z), w, acc[5]);
                acc[6] = fmaf(b2f_lo(v.w), w, acc[6]);
                acc[7] = fmaf(b2f_hi(v.w), w, acc[7]);
            }
        }
        #pragma unroll
        for (int f = 0; f < 8; ++f) {
            acc[f] += __shfl_xor(acc[f], 16);
            acc[f] += __shfl_xor(acc[f], 32);
        }
        if (lane < 16) {
            uint4 o;
            o.x = pack2(acc[0], acc[1]);
            o.y = pack2(acc[2], acc[3]);
            o.z = pack2(acc[4], acc[5]);
            o.w = pack2(acc[6], acc[7]);
            *(uint4*)(agg + (size_t)node * 128 + sl * 8) = o;
        }
    } else {
        float acc[4] = {};
        for (; e + 8 <= end; e += 8) {
            int2 mA = em[e + g];
            int2 mB = em[e + 4 + g];
            uint2 vA = *(const uint2*)(h + (size_t)mA.x * 64 + sl * 4);
            uint2 vB = *(const uint2*)(h + (size_t)mB.x * 64 + sl * 4);
            float wA = __int_as_float(mA.y), wB = __int_as_float(mB.y);
            acc[0] = fmaf(b2f_lo(vA.x), wA, acc[0]);
            acc[1] = fmaf(b2f_hi(vA.x), wA, acc[1]);
            acc[2] = fmaf(b2f_lo(vA.y), wA, acc[2]);
            acc[3] = fmaf(b2f_hi(vA.y), wA, acc[3]);
            acc[0] = fmaf(b2f_lo(vB.x), wB, acc[0]);
            acc[1] = fmaf(b2f_hi(vB.x), wB, acc[1]);
            acc[2] = fmaf(b2f_lo(vB.y), wB, acc[2]);
            acc[3] = fmaf(b2f_hi(vB.y), wB, acc[3]);
        }
        for (; e < end; e += 4) {
            int ej = e + g;
            if (ej < end) {
                int2 m = em[ej];
                uint2 v = *(const uint2*)(h + (size_t)m.x * 64 + sl * 4);
                float w = __int_as_float(m.y);
                acc[0] = fmaf(b2f_lo(v.x), w, acc[0]);
                acc[1] = fmaf(b2f_hi(v.x), w, acc[1]);
                acc[2] = fmaf(b2f_lo(v.y), w, acc[2]);
                acc[3] = fmaf(b2f_hi(v.y), w, acc[3]);
            }
        }
        #pragma unroll
        for (int f = 0; f < 4; ++f) {
            acc[f] += __shfl_xor(acc[f], 16);
            acc[f] += __shfl_xor(acc[f], 32);
        }
        if (lane < 16) {
            uint2 o;
            o.x = pack2(acc[0], acc[1]);
            o.y = pack2(acc[2], acc[3]);
            *(uint2*)(agg + (size_t)node * 64 + sl * 4) = o;
        }
    }
}

// ---------------------------------------------------------------------------
// MFMA GEMM + bias + BN + ReLU. bf16 in, fp32 accum, bf16 out. K = 2F.
// Block: 256 thr = 4 waves, 128 rows x 128 cols; 32 rows/wave (2 m-tiles).
// W panel (pre-converted bf16, [c][k]) copied once to LDS (+8 pad).
// A streamed from global with 1-deep register prefetch across the K-loop.
// ---------------------------------------------------------------------------

template <int F>
__global__ __launch_bounds__(256, 2) void gemm_mfma(const ushort* __restrict__ A0,
                                                    const ushort* __restrict__ A1,
                                                    const ushort* __restrict__ Wb,
                                                    const float* __restrict__ bias,
                                                    const float* __restrict__ bng,
                                                    const float* __restrict__ bnb,
                                                    const float* __restrict__ bnm,
                                                    const float* __restrict__ bnv,
                                                    ushort* __restrict__ out) {
    constexpr int K = 2 * F;
    constexpr int LDW = K + 8;
    __shared__ ushort Wl[128 * LDW];

    int t = threadIdx.x;
    for (int idx = t; idx < 128 * (K / 8); idx += 256) {
        int c  = idx / (K / 8);
        int k8 = (idx % (K / 8)) * 8;
        *(short8*)&Wl[c * LDW + k8] = *(const short8*)&Wb[c * K + k8];
    }
    __syncthreads();

    int wave = t >> 6, lane = t & 63;
    int m = lane & 15, quad = lane >> 4;
    int r0 = blockIdx.x * 128 + wave * 32 + m;
    int r1 = r0 + 16;

    f32x4 acc0[8], acc1[8];
    #pragma unroll
    for (int i = 0; i < 8; ++i) { acc0[i] = (f32x4)(0.f); acc1[i] = (f32x4)(0.f); }

    auto loadA = [&](int row, int k0) -> short8 {
        short8 v = {};
        if (row < N_NODES)
            v = (k0 < F) ? *(const short8*)(A0 + (size_t)row * F + k0)
                         : *(const short8*)(A1 + (size_t)row * F + (k0 - F));
        return v;
    };

    short8 a0 = loadA(r0, quad * 8);
    short8 a1 = loadA(r1, quad * 8);
    for (int kc = 0; kc < K; kc += 32) {
        int k0 = kc + quad * 8;
        short8 na0 = {}, na1 = {};
        if (kc + 32 < K) {
            na0 = loadA(r0, k0 + 32);
            na1 = loadA(r1, k0 + 32);
        }
        #pragma unroll
        for (int ct = 0; ct < 8; ++ct) {
            short8 b = *(const short8*)&Wl[(ct * 16 + m) * LDW + k0];
            acc0[ct] = __builtin_amdgcn_mfma_f32_16x16x32_bf16(a0, b, acc0[ct], 0, 0, 0);
            acc1[ct] = __builtin_amdgcn_mfma_f32_16x16x32_bf16(a1, b, acc1[ct], 0, 0, 0);
        }
        a0 = na0; a1 = na1;
    }

    int rb0 = blockIdx.x * 128 + wave * 32 + quad * 4;
    #pragma unroll
    for (int ct = 0; ct < 8; ++ct) {
        int c = ct * 16 + m;
        float sc = bng[c] * rsqrtf(bnv[c] + EPS);
        float sh = bnb[c] - bnm[c] * sc;
        float bi = bias[c];
        #pragma unroll
        for (int reg = 0; reg < 4; ++reg) {
            int r = rb0 + reg;
            if (r < N_NODES) {
                float v = fmaxf(fmaf(acc0[ct][reg] + bi, sc, sh), 0.f);
                out[(size_t)r * 128 + c] = f2b(v);
            }
            int r2 = rb0 + 16 + reg;
            if (r2 < N_NODES) {
                float v = fmaxf(fmaf(acc1[ct][reg] + bi, sc, sh), 0.f);
                out[(size_t)r2 * 128 + c] = f2b(v);
            }
        }
    }
}

// ---------------------------------------------------------------------------
// Pooling: sorted batch -> run-length accumulate (bf16 in, fp32 atomics out)
// ---------------------------------------------------------------------------

#define POOL_NODES 64
__global__ __launch_bounds__(256) void pool_kernel(const ushort* __restrict__ h,
                                                   const int* __restrict__ batch,
                                                   float* __restrict__ pooled) {
    __shared__ int gb[POOL_NODES];
    int b = blockIdx.x, t = threadIdx.x;
    int n0 = b * POOL_NODES;
    if (t < POOL_NODES) {
        int n = n0 + t;
        gb[t] = (n < N_NODES) ? batch[n] : -1;
    }
    __syncthreads();
    int f = t & 127;
    int half = t >> 7;
    float acc = 0.f;
    int gcur = -1;
    for (int i = half; i < POOL_NODES; i += 2) {
        int n = n0 + i;
        if (n >= N_NODES) break;
        int g = gb[i];
        if (g != gcur) {
            if (gcur >= 0) atomicAdd(&pooled[(size_t)gcur * 128 + f], acc);
            gcur = g;
            acc = 0.f;
        }
        acc += b2f_lo((uint)h[(size_t)n * 128 + f]);
    }
    if (gcur >= 0) atomicAdd(&pooled[(size_t)gcur * 128 + f], acc);
}

// ---------------------------------------------------------------------------
// Head: counts via binary search on sorted batch, one wave per graph
// ---------------------------------------------------------------------------

__global__ __launch_bounds__(64) void head_kernel(const float* __restrict__ pooled,
                                                  const int* __restrict__ batch,
                                                  const float* __restrict__ w1,
                                                  const float* __restrict__ b1,
                                                  const float* __restrict__ w2,
                                                  const float* __restrict__ b2,
                                                  float* __restrict__ out) {
    int g = blockIdx.x;
    int j = threadIdx.x;
    int lo = 0, hi = N_NODES;
    while (lo < hi) { int m = (lo + hi) >> 1; if (batch[m] <  g) lo = m + 1; else hi = m; }
    int start = lo;
    lo = 0; hi = N_NODES;
    while (lo < hi) { int m = (lo + hi) >> 1; if (batch[m] <= g) lo = m + 1; else hi = m; }
    float inv = 1.0f / fmaxf((float)(lo - start), 1.0f);

    float acc = b1[j];
    #pragma unroll 4
    for (int k = 0; k < 128; ++k)
        acc = fmaf(pooled[(size_t)g * 128 + k] * inv, w1[k * 64 + j], acc);
    float prod = fmaxf(acc, 0.f) * w2[j];
    #pragma unroll
    for (int off = 32; off > 0; off >>= 1)
        prod += __shfl_down(prod, off);
    if (j == 0) out[g] = prod + b2[0];
}

// ---------------------------------------------------------------------------

extern "C" void kernel_launch(void* const* d_in, const int* in_sizes, int n_in,
                              void* d_out, int out_size, void* d_ws, size_t ws_size,
                              hipStream_t stream) {
    const float* x     = (const float*)d_in[0];
    const int*   ei    = (const int*)d_in[1];
    const float* ea    = (const float*)d_in[2];
    const int*   batch = (const int*)d_in[3];
    const float* rel_w[3]  = {(const float*)d_in[4],  (const float*)d_in[11], (const float*)d_in[18]};
    const float* rel_b[3]  = {(const float*)d_in[5],  (const float*)d_in[12], (const float*)d_in[19]};
    const float* root_w[3] = {(const float*)d_in[6],  (const float*)d_in[13], (const float*)d_in[20]};
    const float* bn_g[3]   = {(const float*)d_in[7],  (const float*)d_in[14], (const float*)d_in[21]};
    const float* bn_b[3]   = {(const float*)d_in[8],  (const float*)d_in[15], (const float*)d_in[22]};
    const float* bn_m[3]   = {(const float*)d_in[9],  (const float*)d_in[16], (const float*)d_in[23]};
    const float* bn_v[3]   = {(const float*)d_in[10], (const float*)d_in[17], (const float*)d_in[24]};
    const float* head_w1 = (const float*)d_in[25];
    const float* head_b1 = (const float*)d_in[26];
    const float* head_w2 = (const float*)d_in[27];
    const float* head_b2 = (const float*)d_in[28];
    float* out = (float*)d_out;

    // workspace layout (~104 MB)
    char* ws = (char*)d_ws;
    int*    rowptr = (int*)(ws + 0);              // N_NODES+1 ints
    int*    counts = (int*)(ws + 401408);         // SCAN_M ints
    int2*   em     = (int2*)(ws + 524288);        // E int2 (src, ew bits)
    ushort* xb     = (ushort*)(ws + 13631488);    // N*64 bf16
    ushort* h_a    = (ushort*)(ws + 26431488);    // N*128 bf16
    ushort* h_b    = (ushort*)(ws + 52031488);    // N*128 bf16
    ushort* aggb   = (ushort*)(ws + 77631488);    // N*128 bf16 (layer0 uses N*64)
    float*  pooled = (float*)(ws + 103231488);    // 1024*128 fp32
    ushort* wb     = (ushort*)(ws + 103755776);   // 81920 bf16 (3 W panels)
    // sort scratch aliases aggb region (dead until first agg)
    int*    dstb = (int*)(ws + 77631488);         // E ints
    int2*   emb  = (int2*)(ws + 84031488);        // E int2

    ushort* wb0 = wb;            // 128*128
    ushort* wb1 = wb + 16384;    // 128*256
    ushort* wb2 = wb + 49152;    // 128*256

    hipMemsetAsync(pooled, 0, N_GRAPHS * HIDDEN * sizeof(float), stream);

    bin_count_kernel<<<NBLK_A, 256, 0, stream>>>(ei, counts);
    scan_counts_kernel<<<1, 1024, 0, stream>>>(counts, rowptr);
    bin_scatter_kernel<<<NBLK_A, 256, 0, stream>>>(ei, ea, counts, dstb, emb);
    bucket_build_kernel<<<NBUCK, 1024, 0, stream>>>(counts, dstb, emb, rowptr, em);
    cvt_x_kernel<<<(N_NODES * 32 + 255) / 256, 256, 0, stream>>>(x, xb);
    cvt_w_kernel<<<(64 * 128 + 255) / 256, 256, 0, stream>>>(rel_w[0], root_w[0], 64,  wb0);
    cvt_w_kernel<<<(64 * 256 + 255) / 256, 256, 0, stream>>>(rel_w[1], root_w[1], 128, wb1);
    cvt_w_kernel<<<(64 * 256 + 255) / 256, 256, 0, stream>>>(rel_w[2], root_w[2], 128, wb2);

    const int AGG_BLOCKS  = N_NODES / 4;
    const int GEMM_BLOCKS = (N_NODES + 127) / 128;

    agg_kernel<64><<<AGG_BLOCKS, 256, 0, stream>>>(xb, rowptr, em, aggb);
    gemm_mfma<64><<<GEMM_BLOCKS, 256, 0, stream>>>(aggb, xb, wb0, rel_b[0],
                                                   bn_g[0], bn_b[0], bn_m[0], bn_v[0], h_a);
    agg_kernel<128><<<AGG_BLOCKS, 256, 0, stream>>>(h_a, rowptr, em, aggb);
    gemm_mfma<128><<<GEMM_BLOCKS, 256, 0, stream>>>(aggb, h_a, wb1, rel_b[1],
                                                    bn_g[1], bn_b[1], bn_m[1], bn_v[1], h_b);
    agg_kernel<128><<<AGG_BLOCKS, 256, 0, stream>>>(h_b, rowptr, em, aggb);
    gemm_mfma<128><<<GEMM_BLOCKS, 256, 0, stream>>>(aggb, h_b, wb2, rel_b[2],
                                                    bn_g[2], bn_b[2], bn_m[2], bn_v[2], h_a);

    pool_kernel<<<(N_NODES + POOL_NODES - 1) / POOL_NODES, 256, 0, stream>>>(h_a, batch, pooled);
    head_kernel<<<N_GRAPHS, 64, 0, stream>>>(pooled, batch, head_w1, head_b1, head_w2, head_b2, out);
}

// Round 8
// 490.097 us; speedup vs baseline: 2.7388x; 1.0765x over previous
//
#include <hip/hip_runtime.h>

#define N_NODES 100000
#define N_EDGES 1600000
#define F_IN 64
#define HIDDEN 128
#define N_GRAPHS 1024
#define EPS 1e-5f

typedef short short8 __attribute__((ext_vector_type(8)));
typedef float f32x4 __attribute__((ext_vector_type(4)));
typedef unsigned int uint;
typedef unsigned short ushort;

// fp32 -> bf16 round-to-nearest-even (finite values only)
__device__ __forceinline__ ushort f2b(float f) {
    uint x = __float_as_uint(f);
    return (ushort)((x + 0x7fffu + ((x >> 16) & 1u)) >> 16);
}
__device__ __forceinline__ uint pack2(float a, float b) {
    return (uint)f2b(a) | ((uint)f2b(b) << 16);
}
__device__ __forceinline__ float b2f_lo(uint u) { return __uint_as_float(u << 16); }
__device__ __forceinline__ float b2f_hi(uint u) { return __uint_as_float(u & 0xffff0000u); }

// two-level counting sort parameters
#define NBLK_A 128
#define CHUNK ((N_EDGES + NBLK_A - 1) / NBLK_A)        // 12500
#define BUCK_SHIFT 9                                    // 512-node windows
#define NBUCK ((N_NODES + 511) / 512)                   // 196
#define SCAN_M (NBUCK * NBLK_A)                         // 25088
#define SCAN_T ((SCAN_M + 1023) / 1024)                 // 25 tiles

// ---------------------------------------------------------------------------
// CSR build via two-level counting sort (no global atomics)
// ---------------------------------------------------------------------------

__global__ __launch_bounds__(256) void bin_count_kernel(const int* __restrict__ ei,
                                                        int* __restrict__ counts) {
    __shared__ int cnt[NBUCK];
    int blk = blockIdx.x, t = threadIdx.x;
    for (int i = t; i < NBUCK; i += 256) cnt[i] = 0;
    __syncthreads();
    int e0 = blk * CHUNK, e1 = min(e0 + CHUNK, N_EDGES);
    for (int e = e0 + t; e < e1; e += 256)
        atomicAdd(&cnt[ei[N_EDGES + e] >> BUCK_SHIFT], 1);
    __syncthreads();
    for (int i = t; i < NBUCK; i += 256) counts[i * NBLK_A + blk] = cnt[i];
}

// hierarchical exclusive scan of counts[SCAN_M]: reduce -> tiny scan -> apply
__global__ __launch_bounds__(1024) void sc_reduce_kernel(const int* __restrict__ counts,
                                                         int* __restrict__ partial) {
    __shared__ int lds[16];
    int b = blockIdx.x, t = threadIdx.x;
    int i = b * 1024 + t;
    int v = (i < SCAN_M) ? counts[i] : 0;
    #pragma unroll
    for (int off = 32; off > 0; off >>= 1) v += __shfl_down(v, off);
    if ((t & 63) == 0) lds[t >> 6] = v;
    __syncthreads();
    if (t == 0) {
        int s = 0;
        #pragma unroll
        for (int j = 0; j < 16; ++j) s += lds[j];
        partial[b] = s;
    }
}

__global__ __launch_bounds__(64) void sc_small_kernel(int* __restrict__ partial,
                                                      int* __restrict__ rowptr) {
    if (threadIdx.x == 0) {
        int s = 0;
        for (int j = 0; j < SCAN_T; ++j) { int v = partial[j]; partial[j] = s; s += v; }
        rowptr[N_NODES] = N_EDGES;
    }
}

__global__ __launch_bounds__(1024) void sc_apply_kernel(int* __restrict__ counts,
                                                        const int* __restrict__ partial) {
    __shared__ int lds[1024];
    int b = blockIdx.x, t = threadIdx.x;
    int i = b * 1024 + t;
    int v = (i < SCAN_M) ? counts[i] : 0;
    lds[t] = v;
    __syncthreads();
    for (int off = 1; off < 1024; off <<= 1) {
        int x = (t >= off) ? lds[t - off] : 0;
        __syncthreads();
        lds[t] += x;
        __syncthreads();
    }
    if (i < SCAN_M) counts[i] = lds[t] - v + partial[b];
}

// scatter edges into coarse-bucket order; payload packed to one int2:
//   x = src, y = (bf16(w) << 16) | (dst & 511)
__global__ __launch_bounds__(256) void bin_scatter_kernel(const int* __restrict__ ei,
                                                          const float* __restrict__ ea,
                                                          const int* __restrict__ counts,
                                                          int2* __restrict__ emb) {
    __shared__ int cur[NBUCK];
    int blk = blockIdx.x, t = threadIdx.x;
    for (int i = t; i < NBUCK; i += 256) cur[i] = counts[i * NBLK_A + blk];
    __syncthreads();
    int e0 = blk * CHUNK, e1 = min(e0 + CHUNK, N_EDGES);
    for (int e = e0 + t; e < e1; e += 256) {
        int s = ei[e], d = ei[N_EDGES + e];
        uint y = ((uint)f2b(ea[e]) << 16) | (uint)(d & 511);
        int p = atomicAdd(&cur[d >> BUCK_SHIFT], 1);
        emb[p] = make_int2(s, (int)y);
    }
}

// per-bucket exact sort + rowptr; final em: x = src, y = float bits of bf16 w
__global__ __launch_bounds__(1024) void bucket_build_kernel(const int* __restrict__ counts,
                                                            const int2* __restrict__ emb,
                                                            int* __restrict__ rowptr,
                                                            int2* __restrict__ em) {
    __shared__ int hist[512];
    __shared__ int cursor[512];
    int b = blockIdx.x, t = threadIdx.x;
    int beg = counts[b * NBLK_A];
    int end = (b + 1 < NBUCK) ? counts[(b + 1) * NBLK_A] : N_EDGES;
    int nbase = b << BUCK_SHIFT;
    int nnodes = min(512, N_NODES - nbase);

    if (t < 512) hist[t] = 0;
    __syncthreads();
    for (int e = beg + t; e < end; e += 1024)
        atomicAdd(&hist[(uint)emb[e].y & 511u], 1);
    __syncthreads();

    int v = (t < 512) ? hist[t] : 0;
    for (int off = 1; off < 512; off <<= 1) {
        int x = (t < 512 && t >= off) ? hist[t - off] : 0;
        __syncthreads();
        if (t < 512) hist[t] += x;
        __syncthreads();
    }
    if (t < 512) {
        int excl = hist[t] - v;
        cursor[t] = beg + excl;
        if (t < nnodes) rowptr[nbase + t] = beg + excl;
    }
    __syncthreads();

    for (int e = beg + t; e < end; e += 1024) {
        int2 m = emb[e];
        int p = atomicAdd(&cursor[(uint)m.y & 511u], 1);
        em[p] = make_int2(m.x, (int)((uint)m.y & 0xffff0000u));
    }
}

// ---------------------------------------------------------------------------
// Fused prep: x->bf16, 3 W panels ->bf16 [c][k], pooled zero. Flat index.
// ---------------------------------------------------------------------------

#define PREP_X   (N_NODES * 32)       // uints of xb
#define PREP_W0  8192                 // uints of wb0 (128*128/2)
#define PREP_W1  16384                // uints of wb1 (128*256/2)
#define PREP_W2  16384
#define PREP_PZ  (N_GRAPHS * HIDDEN)  // floats of pooled
#define PREP_TOT (PREP_X + PREP_W0 + PREP_W1 + PREP_W2 + PREP_PZ)

__device__ __forceinline__ void cvt_w_elem(const float* W0, const float* W1, int F,
                                           int idx, uint* out) {
    int K = 2 * F;
    int c  = idx / (K / 2);
    int k2 = (idx % (K / 2)) * 2;
    float f0 = (k2 < F) ? W0[k2 * 128 + c] : W1[(k2 - F) * 128 + c];
    float f1 = (k2 + 1 < F) ? W0[(k2 + 1) * 128 + c] : W1[(k2 + 1 - F) * 128 + c];
    out[idx] = pack2(f0, f1);
}

__global__ __launch_bounds__(256) void prep_kernel(const float* __restrict__ x, uint* __restrict__ xb,
                                                   const float* __restrict__ rw0, const float* __restrict__ ow0,
                                                   const float* __restrict__ rw1, const float* __restrict__ ow1,
                                                   const float* __restrict__ rw2, const float* __restrict__ ow2,
                                                   uint* __restrict__ wb0, uint* __restrict__ wb1,
                                                   uint* __restrict__ wb2, float* __restrict__ pooled) {
    int i = blockIdx.x * 256 + threadIdx.x;
    if (i < PREP_X) {
        float2 v = ((const float2*)x)[i];
        xb[i] = pack2(v.x, v.y);
        return;
    }
    i -= PREP_X;
    if (i < PREP_W0) { cvt_w_elem(rw0, ow0, 64, i, wb0); return; }
    i -= PREP_W0;
    if (i < PREP_W1) { cvt_w_elem(rw1, ow1, 128, i, wb1); return; }
    i -= PREP_W1;
    if (i < PREP_W2) { cvt_w_elem(rw2, ow2, 128, i, wb2); return; }
    i -= PREP_W2;
    if (i < PREP_PZ) pooled[i] = 0.f;
}

// ---------------------------------------------------------------------------
// Aggregation: one wave per node, 4 x 16-lane groups; group g handles edge
// e+g, slot covers 16B (F=128) / 8B (F=64) of the row. 2-deep unroll.
// ---------------------------------------------------------------------------

template <int F>
__global__ __launch_bounds__(256) void agg_kernel(const ushort* __restrict__ h,
                                                  const int* __restrict__ rowptr,
                                                  const int2* __restrict__ em,
                                                  ushort* __restrict__ agg) {
    int node = blockIdx.x * 4 + (threadIdx.x >> 6);
    int lane = threadIdx.x & 63;
    int g  = lane >> 4;
    int sl = lane & 15;
    int beg = rowptr[node], end = rowptr[node + 1];
    int e = beg;

    if (F == 128) {
        float acc[8] = {};
        for (; e + 8 <= end; e += 8) {
            int2 mA = em[e + g];
            int2 mB = em[e + 4 + g];
            uint4 vA = *(const uint4*)(h + (size_t)mA.x * 128 + sl * 8);
            uint4 vB = *(const uint4*)(h + (size_t)mB.x * 128 + sl * 8);
            float wA = __int_as_float(mA.y), wB = __int_as_float(mB.y);
            acc[0] = fmaf(b2f_lo(vA.x), wA, acc[0]);
            acc[1] = fmaf(b2f_hi(vA.x), wA, acc[1]);
            acc[2] = fmaf(b2f_lo(vA.y), wA, acc[2]);
            acc[3] = fmaf(b2f_hi(vA.y), wA, acc[3]);
            acc[4] = fmaf(b2f_lo(vA.z), wA, acc[4]);
            acc[5] = fmaf(b2f_hi(vA.z), wA, acc[5]);
            acc[6] = fmaf(b2f_lo(vA.w), wA, acc[6]);
            acc[7] = fmaf(b2f_hi(vA.w), wA, acc[7]);
            acc[0] = fmaf(b2f_lo(vB.x), wB, acc[0]);
            acc[1] = fmaf(b2f_hi(vB.x), wB, acc[1]);
            acc[2] = fmaf(b2f_lo(vB.y), wB, acc[2]);
            acc[3] = fmaf(b2f_hi(vB.y), wB, acc[3]);
            acc[4] = fmaf(b2f_lo(vB.z), wB, acc[4]);
            acc[5] = fmaf(b2f_hi(vB.z), wB, acc[5]);
            acc[6] = fmaf(b2f_lo(vB.w), wB, acc[6]);
            acc[7] = fmaf(b2f_hi(vB.w), wB, acc[7]);
        }
        for (; e < end; e += 4) {
            int ej = e + g;
            if (ej < end) {
                int2 m = em[ej];
                uint4 v = *(const uint4*)(h + (size_t)m.x * 128 + sl * 8);
                float w = __int_as_float(m.y);
                acc[0] = fmaf(b2f_lo(v.x), w, acc[0]);
                acc[1] = fmaf(b2f_hi(v.x), w, acc[1]);
                acc[2] = fmaf(b2f_lo(v.y), w, acc[2]);
                acc[3] = fmaf(b2f_hi(v.y), w, acc[3]);
                acc[4] = fmaf(b2f_lo(v.z), w, acc[4]);
                acc[5] = fmaf(b2f_hi(v.z), w, acc[5]);
                acc[6] = fmaf(b2f_lo(v.w), w, acc[6]);
                acc[7] = fmaf(b2f_hi(v.w), w, acc[7]);
            }
        }
        #pragma unroll
        for (int f = 0; f < 8; ++f) {
            acc[f] += __shfl_xor(acc[f], 16);
            acc[f] += __shfl_xor(acc[f], 32);
        }
        if (lane < 16) {
            uint4 o;
            o.x = pack2(acc[0], acc[1]);
            o.y = pack2(acc[2], acc[3]);
            o.z = pack2(acc[4], acc[5]);
            o.w = pack2(acc[6], acc[7]);
            *(uint4*)(agg + (size_t)node * 128 + sl * 8) = o;
        }
    } else {
        float acc[4] = {};
        for (; e + 8 <= end; e += 8) {
            int2 mA = em[e + g];
            int2 mB = em[e + 4 + g];
            uint2 vA = *(const uint2*)(h + (size_t)mA.x * 64 + sl * 4);
            uint2 vB = *(const uint2*)(h + (size_t)mB.x * 64 + sl * 4);
            float wA = __int_as_float(mA.y), wB = __int_as_float(mB.y);
            acc[0] = fmaf(b2f_lo(vA.x), wA, acc[0]);
            acc[1] = fmaf(b2f_hi(vA.x), wA, acc[1]);
            acc[2] = fmaf(b2f_lo(vA.y), wA, acc[2]);
            acc[3] = fmaf(b2f_hi(vA.y), wA, acc[3]);
            acc[0] = fmaf(b2f_lo(vB.x), wB, acc[0]);
            acc[1] = fmaf(b2f_hi(vB.x), wB, acc[1]);
            acc[2] = fmaf(b2f_lo(vB.y), wB, acc[2]);
            acc[3] = fmaf(b2f_hi(vB.y), wB, acc[3]);
        }
        for (; e < end; e += 4) {
            int ej = e + g;
            if (ej < end) {
                int2 m = em[ej];
                uint2 v = *(const uint2*)(h + (size_t)m.x * 64 + sl * 4);
                float w = __int_as_float(m.y);
                acc[0] = fmaf(b2f_lo(v.x), w, acc[0]);
                acc[1] = fmaf(b2f_hi(v.x), w, acc[1]);
                acc[2] = fmaf(b2f_lo(v.y), w, acc[2]);
                acc[3] = fmaf(b2f_hi(v.y), w, acc[3]);
            }
        }
        #pragma unroll
        for (int f = 0; f < 4; ++f) {
            acc[f] += __shfl_xor(acc[f], 16);
            acc[f] += __shfl_xor(acc[f], 32);
        }
        if (lane < 16) {
            uint2 o;
            o.x = pack2(acc[0], acc[1]);
            o.y = pack2(acc[2], acc[3]);
            *(uint2*)(agg + (size_t)node * 64 + sl * 4) = o;
        }
    }
}

// ---------------------------------------------------------------------------
// MFMA GEMM + bias + BN + ReLU. bf16 in, fp32 accum, bf16 out. K = 2F.
// 256 thr = 4 waves, 128 rows x 128 cols; 32 rows/wave. W panel in LDS.
// A streamed with 1-deep register prefetch.
// ---------------------------------------------------------------------------

template <int F>
__global__ __launch_bounds__(256, 2) void gemm_mfma(const ushort* __restrict__ A0,
                                                    const ushort* __restrict__ A1,
                                                    const ushort* __restrict__ Wb,
                                                    const float* __restrict__ bias,
                                                    const float* __restrict__ bng,
                                                    const float* __restrict__ bnb,
                                                    const float* __restrict__ bnm,
                                                    const float* __restrict__ bnv,
                                                    ushort* __restrict__ out) {
    constexpr int K = 2 * F;
    constexpr int LDW = K + 8;
    __shared__ ushort Wl[128 * LDW];

    int t = threadIdx.x;
    for (int idx = t; idx < 128 * (K / 8); idx += 256) {
        int c  = idx / (K / 8);
        int k8 = (idx % (K / 8)) * 8;
        *(short8*)&Wl[c * LDW + k8] = *(const short8*)&Wb[c * K + k8];
    }
    __syncthreads();

    int wave = t >> 6, lane = t & 63;
    int m = lane & 15, quad = lane >> 4;
    int r0 = blockIdx.x * 128 + wave * 32 + m;
    int r1 = r0 + 16;

    f32x4 acc0[8], acc1[8];
    #pragma unroll
    for (int i = 0; i < 8; ++i) { acc0[i] = (f32x4)(0.f); acc1[i] = (f32x4)(0.f); }

    auto loadA = [&](int row, int k0) -> short8 {
        short8 v = {};
        if (row < N_NODES)
            v = (k0 < F) ? *(const short8*)(A0 + (size_t)row * F + k0)
                         : *(const short8*)(A1 + (size_t)row * F + (k0 - F));
        return v;
    };

    short8 a0 = loadA(r0, quad * 8);
    short8 a1 = loadA(r1, quad * 8);
    for (int kc = 0; kc < K; kc += 32) {
        int k0 = kc + quad * 8;
        short8 na0 = {}, na1 = {};
        if (kc + 32 < K) {
            na0 = loadA(r0, k0 + 32);
            na1 = loadA(r1, k0 + 32);
        }
        #pragma unroll
        for (int ct = 0; ct < 8; ++ct) {
            short8 b = *(const short8*)&Wl[(ct * 16 + m) * LDW + k0];
            acc0[ct] = __builtin_amdgcn_mfma_f32_16x16x32_bf16(a0, b, acc0[ct], 0, 0, 0);
            acc1[ct] = __builtin_amdgcn_mfma_f32_16x16x32_bf16(a1, b, acc1[ct], 0, 0, 0);
        }
        a0 = na0; a1 = na1;
    }

    int rb0 = blockIdx.x * 128 + wave * 32 + quad * 4;
    #pragma unroll
    for (int ct = 0; ct < 8; ++ct) {
        int c = ct * 16 + m;
        float sc = bng[c] * rsqrtf(bnv[c] + EPS);
        float sh = bnb[c] - bnm[c] * sc;
        float bi = bias[c];
        #pragma unroll
        for (int reg = 0; reg < 4; ++reg) {
            int r = rb0 + reg;
            if (r < N_NODES) {
                float v = fmaxf(fmaf(acc0[ct][reg] + bi, sc, sh), 0.f);
                out[(size_t)r * 128 + c] = f2b(v);
            }
            int r2 = rb0 + 16 + reg;
            if (r2 < N_NODES) {
                float v = fmaxf(fmaf(acc1[ct][reg] + bi, sc, sh), 0.f);
                out[(size_t)r2 * 128 + c] = f2b(v);
            }
        }
    }
}

// ---------------------------------------------------------------------------
// Pooling: sorted batch -> run-length accumulate; uint loads (2 feats/lane)
// ---------------------------------------------------------------------------

#define POOL_NODES 64
__global__ __launch_bounds__(256) void pool_kernel(const ushort* __restrict__ h,
                                                   const int* __restrict__ batch,
                                                   float* __restrict__ pooled) {
    __shared__ int gb[POOL_NODES];
    int b = blockIdx.x, t = threadIdx.x;
    int n0 = b * POOL_NODES;
    if (t < POOL_NODES) {
        int n = n0 + t;
        gb[t] = (n < N_NODES) ? batch[n] : -1;
    }
    __syncthreads();
    int f2 = t & 63;   // uint index: features {2*f2, 2*f2+1}
    int q  = t >> 6;   // 4-way node parallel
    const uint* hp = (const uint*)h;
    float alo = 0.f, ahi = 0.f;
    int gcur = -1;
    for (int i = q; i < POOL_NODES; i += 4) {
        int n = n0 + i;
        if (n >= N_NODES) break;
        int g = gb[i];
        if (g != gcur) {
            if (gcur >= 0) {
                atomicAdd(&pooled[(size_t)gcur * 128 + f2 * 2], alo);
                atomicAdd(&pooled[(size_t)gcur * 128 + f2 * 2 + 1], ahi);
            }
            gcur = g;
            alo = 0.f; ahi = 0.f;
        }
        uint u = hp[(size_t)n * 64 + f2];
        alo += b2f_lo(u);
        ahi += b2f_hi(u);
    }
    if (gcur >= 0) {
        atomicAdd(&pooled[(size_t)gcur * 128 + f2 * 2], alo);
        atomicAdd(&pooled[(size_t)gcur * 128 + f2 * 2 + 1], ahi);
    }
}

// ---------------------------------------------------------------------------
// Head: counts via binary search on sorted batch, one wave per graph
// ---------------------------------------------------------------------------

__global__ __launch_bounds__(64) void head_kernel(const float* __restrict__ pooled,
                                                  const int* __restrict__ batch,
                                                  const float* __restrict__ w1,
                                                  const float* __restrict__ b1,
                                                  const float* __restrict__ w2,
                                                  const float* __restrict__ b2,
                                                  float* __restrict__ out) {
    int g = blockIdx.x;
    int j = threadIdx.x;
    int lo = 0, hi = N_NODES;
    while (lo < hi) { int m = (lo + hi) >> 1; if (batch[m] <  g) lo = m + 1; else hi = m; }
    int start = lo;
    lo = 0; hi = N_NODES;
    while (lo < hi) { int m = (lo + hi) >> 1; if (batch[m] <= g) lo = m + 1; else hi = m; }
    float inv = 1.0f / fmaxf((float)(lo - start), 1.0f);

    float acc = b1[j];
    #pragma unroll 4
    for (int k = 0; k < 128; ++k)
        acc = fmaf(pooled[(size_t)g * 128 + k] * inv, w1[k * 64 + j], acc);
    float prod = fmaxf(acc, 0.f) * w2[j];
    #pragma unroll
    for (int off = 32; off > 0; off >>= 1)
        prod += __shfl_down(prod, off);
    if (j == 0) out[g] = prod + b2[0];
}

// ---------------------------------------------------------------------------

extern "C" void kernel_launch(void* const* d_in, const int* in_sizes, int n_in,
                              void* d_out, int out_size, void* d_ws, size_t ws_size,
                              hipStream_t stream) {
    const float* x     = (const float*)d_in[0];
    const int*   ei    = (const int*)d_in[1];
    const float* ea    = (const float*)d_in[2];
    const int*   batch = (const int*)d_in[3];
    const float* rel_w[3]  = {(const float*)d_in[4],  (const float*)d_in[11], (const float*)d_in[18]};
    const float* rel_b[3]  = {(const float*)d_in[5],  (const float*)d_in[12], (const float*)d_in[19]};
    const float* root_w[3] = {(const float*)d_in[6],  (const float*)d_in[13], (const float*)d_in[20]};
    const float* bn_g[3]   = {(const float*)d_in[7],  (const float*)d_in[14], (const float*)d_in[21]};
    const float* bn_b[3]   = {(const float*)d_in[8],  (const float*)d_in[15], (const float*)d_in[22]};
    const float* bn_m[3]   = {(const float*)d_in[9],  (const float*)d_in[16], (const float*)d_in[23]};
    const float* bn_v[3]   = {(const float*)d_in[10], (const float*)d_in[17], (const float*)d_in[24]};
    const float* head_w1 = (const float*)d_in[25];
    const float* head_b1 = (const float*)d_in[26];
    const float* head_w2 = (const float*)d_in[27];
    const float* head_b2 = (const float*)d_in[28];
    float* out = (float*)d_out;

    // workspace layout (~104 MB)
    char* ws = (char*)d_ws;
    int*    rowptr  = (int*)(ws + 0);             // N_NODES+1 ints
    int*    counts  = (int*)(ws + 401408);        // SCAN_M ints
    int*    partial = (int*)(ws + 503808);        // SCAN_T ints
    int2*   em      = (int2*)(ws + 524288);       // E int2 (src, bf16 w bits)
    ushort* xb      = (ushort*)(ws + 13631488);   // N*64 bf16
    ushort* h_a     = (ushort*)(ws + 26431488);   // N*128 bf16
    ushort* h_b     = (ushort*)(ws + 52031488);   // N*128 bf16
    ushort* aggb    = (ushort*)(ws + 77631488);   // N*128 bf16 (layer0 uses N*64)
    float*  pooled  = (float*)(ws + 103231488);   // 1024*128 fp32
    ushort* wb      = (ushort*)(ws + 103755776);  // 81920 bf16 (3 W panels)
    // sort scratch aliases aggb region (dead until first agg)
    int2*   emb = (int2*)(ws + 77631488);         // E int2 packed

    ushort* wb0 = wb;            // 128*128
    ushort* wb1 = wb + 16384;    // 128*256
    ushort* wb2 = wb + 49152;    // 128*256

    prep_kernel<<<(PREP_TOT + 255) / 256, 256, 0, stream>>>(
        x, (uint*)xb, rel_w[0], root_w[0], rel_w[1], root_w[1], rel_w[2], root_w[2],
        (uint*)wb0, (uint*)wb1, (uint*)wb2, pooled);

    bin_count_kernel<<<NBLK_A, 256, 0, stream>>>(ei, counts);
    sc_reduce_kernel<<<SCAN_T, 1024, 0, stream>>>(counts, partial);
    sc_small_kernel<<<1, 64, 0, stream>>>(partial, rowptr);
    sc_apply_kernel<<<SCAN_T, 1024, 0, stream>>>(counts, partial);
    bin_scatter_kernel<<<NBLK_A, 256, 0, stream>>>(ei, ea, counts, emb);
    bucket_build_kernel<<<NBUCK, 1024, 0, stream>>>(counts, emb, rowptr, em);

    const int AGG_BLOCKS  = N_NODES / 4;
    const int GEMM_BLOCKS = (N_NODES + 127) / 128;

    agg_kernel<64><<<AGG_BLOCKS, 256, 0, stream>>>(xb, rowptr, em, aggb);
    gemm_mfma<64><<<GEMM_BLOCKS, 256, 0, stream>>>(aggb, xb, wb0, rel_b[0],
                                                   bn_g[0], bn_b[0], bn_m[0], bn_v[0], h_a);
    agg_kernel<128><<<AGG_BLOCKS, 256, 0, stream>>>(h_a, rowptr, em, aggb);
    gemm_mfma<128><<<GEMM_BLOCKS, 256, 0, stream>>>(aggb, h_a, wb1, rel_b[1],
                                                    bn_g[1], bn_b[1], bn_m[1], bn_v[1], h_b);
    agg_kernel<128><<<AGG_BLOCKS, 256, 0, stream>>>(h_b, rowptr, em, aggb);
    gemm_mfma<128><<<GEMM_BLOCKS, 256, 0, stream>>>(aggb, h_b, wb2, rel_b[2],
                                                    bn_g[2], bn_b[2], bn_m[2], bn_v[2], h_a);

    pool_kernel<<<(N_NODES + POOL_NODES - 1) / POOL_NODES, 256, 0, stream>>>(h_a, batch, pooled);
    head_kernel<<<N_GRAPHS, 64, 0, stream>>>(pooled, batch, head_w1, head_b1, head_w2, head_b2, out);
}

// Round 9
// 454.029 us; speedup vs baseline: 2.9564x; 1.0794x over previous
//
#include <hip/hip_runtime.h>

#define N_NODES 100000
#define N_EDGES 1600000
#define F_IN 64
#define HIDDEN 128
#define N_GRAPHS 1024
#define EPS 1e-5f

typedef short short8 __attribute__((ext_vector_type(8)));
typedef float f32x4 __attribute__((ext_vector_type(4)));
typedef unsigned int uint;
typedef unsigned short ushort;

// fp32 -> bf16 round-to-nearest-even (finite values only)
__device__ __forceinline__ ushort f2b(float f) {
    uint x = __float_as_uint(f);
    return (ushort)((x + 0x7fffu + ((x >> 16) & 1u)) >> 16);
}
__device__ __forceinline__ uint pack2(float a, float b) {
    return (uint)f2b(a) | ((uint)f2b(b) << 16);
}
__device__ __forceinline__ float b2f_lo(uint u) { return __uint_as_float(u << 16); }
__device__ __forceinline__ float b2f_hi(uint u) { return __uint_as_float(u & 0xffff0000u); }

// two-level counting sort parameters
#define NBLK_A 128
#define CHUNK ((N_EDGES + NBLK_A - 1) / NBLK_A)        // 12500
#define BUCK_SHIFT 9                                    // 512-node windows
#define NBUCK ((N_NODES + 511) / 512)                   // 196
#define SCAN_M (NBUCK * NBLK_A)                         // 25088
#define SCAN_T ((SCAN_M + 1023) / 1024)                 // 25 tiles

// ---------------------------------------------------------------------------
// Fused prep (x->bf16, W->bf16 [c][k], pooled zero) + bin_count.
// Blocks [0, NBLK_A) do the edge histogram; the rest do flat elementwise prep.
// ---------------------------------------------------------------------------

#define PREP_X   (N_NODES * 32)       // uints of xb
#define PREP_W0  8192                 // uints of wb0 (128*128/2)
#define PREP_W1  16384                // uints of wb1 (128*256/2)
#define PREP_W2  16384
#define PREP_PZ  (N_GRAPHS * HIDDEN)  // floats of pooled
#define PREP_TOT (PREP_X + PREP_W0 + PREP_W1 + PREP_W2 + PREP_PZ)

__device__ __forceinline__ void cvt_w_elem(const float* W0, const float* W1, int F,
                                           int idx, uint* out) {
    int K = 2 * F;
    int c  = idx / (K / 2);
    int k2 = (idx % (K / 2)) * 2;
    float f0 = (k2 < F) ? W0[k2 * 128 + c] : W1[(k2 - F) * 128 + c];
    float f1 = (k2 + 1 < F) ? W0[(k2 + 1) * 128 + c] : W1[(k2 + 1 - F) * 128 + c];
    out[idx] = pack2(f0, f1);
}

__global__ __launch_bounds__(256) void prep_count_kernel(
        const float* __restrict__ x, uint* __restrict__ xb,
        const float* __restrict__ rw0, const float* __restrict__ ow0,
        const float* __restrict__ rw1, const float* __restrict__ ow1,
        const float* __restrict__ rw2, const float* __restrict__ ow2,
        uint* __restrict__ wb0, uint* __restrict__ wb1,
        uint* __restrict__ wb2, float* __restrict__ pooled,
        const int* __restrict__ ei, int* __restrict__ counts) {
    __shared__ int cnt[NBUCK];
    int t = threadIdx.x;
    if (blockIdx.x < NBLK_A) {
        int blk = blockIdx.x;
        for (int i = t; i < NBUCK; i += 256) cnt[i] = 0;
        __syncthreads();
        int e0 = blk * CHUNK, e1 = min(e0 + CHUNK, N_EDGES);
        for (int e = e0 + t; e < e1; e += 256)
            atomicAdd(&cnt[ei[N_EDGES + e] >> BUCK_SHIFT], 1);
        __syncthreads();
        for (int i = t; i < NBUCK; i += 256) counts[i * NBLK_A + blk] = cnt[i];
        return;
    }
    int i = (blockIdx.x - NBLK_A) * 256 + t;
    if (i < PREP_X) {
        float2 v = ((const float2*)x)[i];
        xb[i] = pack2(v.x, v.y);
        return;
    }
    i -= PREP_X;
    if (i < PREP_W0) { cvt_w_elem(rw0, ow0, 64, i, wb0); return; }
    i -= PREP_W0;
    if (i < PREP_W1) { cvt_w_elem(rw1, ow1, 128, i, wb1); return; }
    i -= PREP_W1;
    if (i < PREP_W2) { cvt_w_elem(rw2, ow2, 128, i, wb2); return; }
    i -= PREP_W2;
    if (i < PREP_PZ) pooled[i] = 0.f;
}

// ---------------------------------------------------------------------------
// Hierarchical exclusive scan of counts[SCAN_M]
// ---------------------------------------------------------------------------

__global__ __launch_bounds__(1024) void sc_reduce_kernel(const int* __restrict__ counts,
                                                         int* __restrict__ partial) {
    __shared__ int lds[16];
    int b = blockIdx.x, t = threadIdx.x;
    int i = b * 1024 + t;
    int v = (i < SCAN_M) ? counts[i] : 0;
    #pragma unroll
    for (int off = 32; off > 0; off >>= 1) v += __shfl_down(v, off);
    if ((t & 63) == 0) lds[t >> 6] = v;
    __syncthreads();
    if (t == 0) {
        int s = 0;
        #pragma unroll
        for (int j = 0; j < 16; ++j) s += lds[j];
        partial[b] = s;
    }
}

// apply: each block derives its own tile offset from raw partials (fused scan)
__global__ __launch_bounds__(1024) void sc_apply_kernel(int* __restrict__ counts,
                                                        const int* __restrict__ partial,
                                                        int* __restrict__ rowptr) {
    __shared__ int lds[1024];
    __shared__ int base;
    int b = blockIdx.x, t = threadIdx.x;
    if (t == 0) {
        int s = 0;
        for (int j = 0; j < b; ++j) s += partial[j];
        base = s;
        if (b == 0) rowptr[N_NODES] = N_EDGES;
    }
    int i = b * 1024 + t;
    int v = (i < SCAN_M) ? counts[i] : 0;
    lds[t] = v;
    __syncthreads();
    for (int off = 1; off < 1024; off <<= 1) {
        int x = (t >= off) ? lds[t - off] : 0;
        __syncthreads();
        lds[t] += x;
        __syncthreads();
    }
    if (i < SCAN_M) counts[i] = lds[t] - v + base;
}

// scatter edges into coarse-bucket order; payload packed to one int2:
//   x = src, y = (bf16(w) << 16) | (dst & 511)
__global__ __launch_bounds__(256) void bin_scatter_kernel(const int* __restrict__ ei,
                                                          const float* __restrict__ ea,
                                                          const int* __restrict__ counts,
                                                          int2* __restrict__ emb) {
    __shared__ int cur[NBUCK];
    int blk = blockIdx.x, t = threadIdx.x;
    for (int i = t; i < NBUCK; i += 256) cur[i] = counts[i * NBLK_A + blk];
    __syncthreads();
    int e0 = blk * CHUNK, e1 = min(e0 + CHUNK, N_EDGES);
    for (int e = e0 + t; e < e1; e += 256) {
        int s = ei[e], d = ei[N_EDGES + e];
        uint y = ((uint)f2b(ea[e]) << 16) | (uint)(d & 511);
        int p = atomicAdd(&cur[d >> BUCK_SHIFT], 1);
        emb[p] = make_int2(s, (int)y);
    }
}

// per-bucket exact sort + rowptr; final em: x = src, y = float bits of bf16 w
__global__ __launch_bounds__(1024) void bucket_build_kernel(const int* __restrict__ counts,
                                                            const int2* __restrict__ emb,
                                                            int* __restrict__ rowptr,
                                                            int2* __restrict__ em) {
    __shared__ int hist[512];
    __shared__ int cursor[512];
    int b = blockIdx.x, t = threadIdx.x;
    int beg = counts[b * NBLK_A];
    int end = (b + 1 < NBUCK) ? counts[(b + 1) * NBLK_A] : N_EDGES;
    int nbase = b << BUCK_SHIFT;
    int nnodes = min(512, N_NODES - nbase);

    if (t < 512) hist[t] = 0;
    __syncthreads();
    for (int e = beg + t; e < end; e += 1024)
        atomicAdd(&hist[(uint)emb[e].y & 511u], 1);
    __syncthreads();

    int v = (t < 512) ? hist[t] : 0;
    for (int off = 1; off < 512; off <<= 1) {
        int x = (t < 512 && t >= off) ? hist[t - off] : 0;
        __syncthreads();
        if (t < 512) hist[t] += x;
        __syncthreads();
    }
    if (t < 512) {
        int excl = hist[t] - v;
        cursor[t] = beg + excl;
        if (t < nnodes) rowptr[nbase + t] = beg + excl;
    }
    __syncthreads();

    for (int e = beg + t; e < end; e += 1024) {
        int2 m = emb[e];
        int p = atomicAdd(&cursor[(uint)m.y & 511u], 1);
        em[p] = make_int2(m.x, (int)((uint)m.y & 0xffff0000u));
    }
}

// ---------------------------------------------------------------------------
// Aggregation: one wave per node, 4 x 16-lane groups; group g handles edge
// e+g, slot covers 16B (F=128) / 8B (F=64) of the row. 2-deep unroll.
// ---------------------------------------------------------------------------

template <int F>
__global__ __launch_bounds__(256) void agg_kernel(const ushort* __restrict__ h,
                                                  const int* __restrict__ rowptr,
                                                  const int2* __restrict__ em,
                                                  ushort* __restrict__ agg) {
    int node = blockIdx.x * 4 + (threadIdx.x >> 6);
    int lane = threadIdx.x & 63;
    int g  = lane >> 4;
    int sl = lane & 15;
    int beg = rowptr[node], end = rowptr[node + 1];
    int e = beg;

    if (F == 128) {
        float acc[8] = {};
        for (; e + 8 <= end; e += 8) {
            int2 mA = em[e + g];
            int2 mB = em[e + 4 + g];
            uint4 vA = *(const uint4*)(h + (size_t)mA.x * 128 + sl * 8);
            uint4 vB = *(const uint4*)(h + (size_t)mB.x * 128 + sl * 8);
            float wA = __int_as_float(mA.y), wB = __int_as_float(mB.y);
            acc[0] = fmaf(b2f_lo(vA.x), wA, acc[0]);
            acc[1] = fmaf(b2f_hi(vA.x), wA, acc[1]);
            acc[2] = fmaf(b2f_lo(vA.y), wA, acc[2]);
            acc[3] = fmaf(b2f_hi(vA.y), wA, acc[3]);
            acc[4] = fmaf(b2f_lo(vA.z), wA, acc[4]);
            acc[5] = fmaf(b2f_hi(vA.z), wA, acc[5]);
            acc[6] = fmaf(b2f_lo(vA.w), wA, acc[6]);
            acc[7] = fmaf(b2f_hi(vA.w), wA, acc[7]);
            acc[0] = fmaf(b2f_lo(vB.x), wB, acc[0]);
            acc[1] = fmaf(b2f_hi(vB.x), wB, acc[1]);
            acc[2] = fmaf(b2f_lo(vB.y), wB, acc[2]);
            acc[3] = fmaf(b2f_hi(vB.y), wB, acc[3]);
            acc[4] = fmaf(b2f_lo(vB.z), wB, acc[4]);
            acc[5] = fmaf(b2f_hi(vB.z), wB, acc[5]);
            acc[6] = fmaf(b2f_lo(vB.w), wB, acc[6]);
            acc[7] = fmaf(b2f_hi(vB.w), wB, acc[7]);
        }
        for (; e < end; e += 4) {
            int ej = e + g;
            if (ej < end) {
                int2 m = em[ej];
                uint4 v = *(const uint4*)(h + (size_t)m.x * 128 + sl * 8);
                float w = __int_as_float(m.y);
                acc[0] = fmaf(b2f_lo(v.x), w, acc[0]);
                acc[1] = fmaf(b2f_hi(v.x), w, acc[1]);
                acc[2] = fmaf(b2f_lo(v.y), w, acc[2]);
                acc[3] = fmaf(b2f_hi(v.y), w, acc[3]);
                acc[4] = fmaf(b2f_lo(v.z), w, acc[4]);
                acc[5] = fmaf(b2f_hi(v.z), w, acc[5]);
                acc[6] = fmaf(b2f_lo(v.w), w, acc[6]);
                acc[7] = fmaf(b2f_hi(v.w), w, acc[7]);
            }
        }
        #pragma unroll
        for (int f = 0; f < 8; ++f) {
            acc[f] += __shfl_xor(acc[f], 16);
            acc[f] += __shfl_xor(acc[f], 32);
        }
        if (lane < 16) {
            uint4 o;
            o.x = pack2(acc[0], acc[1]);
            o.y = pack2(acc[2], acc[3]);
            o.z = pack2(acc[4], acc[5]);
            o.w = pack2(acc[6], acc[7]);
            *(uint4*)(agg + (size_t)node * 128 + sl * 8) = o;
        }
    } else {
        float acc[4] = {};
        for (; e + 8 <= end; e += 8) {
            int2 mA = em[e + g];
            int2 mB = em[e + 4 + g];
            uint2 vA = *(const uint2*)(h + (size_t)mA.x * 64 + sl * 4);
            uint2 vB = *(const uint2*)(h + (size_t)mB.x * 64 + sl * 4);
            float wA = __int_as_float(mA.y), wB = __int_as_float(mB.y);
            acc[0] = fmaf(b2f_lo(vA.x), wA, acc[0]);
            acc[1] = fmaf(b2f_hi(vA.x), wA, acc[1]);
            acc[2] = fmaf(b2f_lo(vA.y), wA, acc[2]);
            acc[3] = fmaf(b2f_hi(vA.y), wA, acc[3]);
            acc[0] = fmaf(b2f_lo(vB.x), wB, acc[0]);
            acc[1] = fmaf(b2f_hi(vB.x), wB, acc[1]);
            acc[2] = fmaf(b2f_lo(vB.y), wB, acc[2]);
            acc[3] = fmaf(b2f_hi(vB.y), wB, acc[3]);
        }
        for (; e < end; e += 4) {
            int ej = e + g;
            if (ej < end) {
                int2 m = em[ej];
                uint2 v = *(const uint2*)(h + (size_t)m.x * 64 + sl * 4);
                float w = __int_as_float(m.y);
                acc[0] = fmaf(b2f_lo(v.x), w, acc[0]);
                acc[1] = fmaf(b2f_hi(v.x), w, acc[1]);
                acc[2] = fmaf(b2f_lo(v.y), w, acc[2]);
                acc[3] = fmaf(b2f_hi(v.y), w, acc[3]);
            }
        }
        #pragma unroll
        for (int f = 0; f < 4; ++f) {
            acc[f] += __shfl_xor(acc[f], 16);
            acc[f] += __shfl_xor(acc[f], 32);
        }
        if (lane < 16) {
            uint2 o;
            o.x = pack2(acc[0], acc[1]);
            o.y = pack2(acc[2], acc[3]);
            *(uint2*)(agg + (size_t)node * 64 + sl * 4) = o;
        }
    }
}

// ---------------------------------------------------------------------------
// MFMA GEMM + bias + BN + ReLU. bf16 in, fp32 accum, bf16 out. K = 2F.
// K-split LDS: W half-panel [128][F+8] (35 KB @F=128) -> 4 blocks/CU,
// 16 waves/CU. half 0: A0 (agg) x W_rel; half 1: A1 (h) x W_root.
// Same MFMA order as the monolithic version -> bit-identical results.
// ---------------------------------------------------------------------------

template <int F>
__global__ __launch_bounds__(256, 4) void gemm_mfma(const ushort* __restrict__ A0,
                                                    const ushort* __restrict__ A1,
                                                    const ushort* __restrict__ Wb,
                                                    const float* __restrict__ bias,
                                                    const float* __restrict__ bng,
                                                    const float* __restrict__ bnb,
                                                    const float* __restrict__ bnm,
                                                    const float* __restrict__ bnv,
                                                    ushort* __restrict__ out) {
    constexpr int K = 2 * F;
    constexpr int LDW = F + 8;
    __shared__ ushort Wl[128 * LDW];

    int t = threadIdx.x;
    int wave = t >> 6, lane = t & 63;
    int m = lane & 15, quad = lane >> 4;
    int r0 = blockIdx.x * 128 + wave * 32 + m;
    int r1 = r0 + 16;

    f32x4 acc0[8], acc1[8];
    #pragma unroll
    for (int i = 0; i < 8; ++i) { acc0[i] = (f32x4)(0.f); acc1[i] = (f32x4)(0.f); }

    #pragma unroll
    for (int half = 0; half < 2; ++half) {
        const ushort* A = half ? A1 : A0;
        // fill half-panel: Wl[c][k] <- Wb[c][half*F + k], 16B chunks
        for (int idx = t; idx < 128 * (F / 8); idx += 256) {
            int c  = idx / (F / 8);
            int k8 = (idx % (F / 8)) * 8;
            *(short8*)&Wl[c * LDW + k8] = *(const short8*)&Wb[c * K + half * F + k8];
        }
        __syncthreads();

        auto loadA = [&](int row, int k0) -> short8 {
            short8 v = {};
            if (row < N_NODES) v = *(const short8*)(A + (size_t)row * F + k0);
            return v;
        };

        short8 a0 = loadA(r0, quad * 8);
        short8 a1 = loadA(r1, quad * 8);
        for (int kc = 0; kc < F; kc += 32) {
            int k0 = kc + quad * 8;
            short8 na0 = {}, na1 = {};
            if (kc + 32 < F) {
                na0 = loadA(r0, k0 + 32);
                na1 = loadA(r1, k0 + 32);
            }
            #pragma unroll
            for (int ct = 0; ct < 8; ++ct) {
                short8 b = *(const short8*)&Wl[(ct * 16 + m) * LDW + k0];
                acc0[ct] = __builtin_amdgcn_mfma_f32_16x16x32_bf16(a0, b, acc0[ct], 0, 0, 0);
                acc1[ct] = __builtin_amdgcn_mfma_f32_16x16x32_bf16(a1, b, acc1[ct], 0, 0, 0);
            }
            a0 = na0; a1 = na1;
        }
        __syncthreads();
    }

    int rb0 = blockIdx.x * 128 + wave * 32 + quad * 4;
    #pragma unroll
    for (int ct = 0; ct < 8; ++ct) {
        int c = ct * 16 + m;
        float sc = bng[c] * rsqrtf(bnv[c] + EPS);
        float sh = bnb[c] - bnm[c] * sc;
        float bi = bias[c];
        #pragma unroll
        for (int reg = 0; reg < 4; ++reg) {
            int r = rb0 + reg;
            if (r < N_NODES) {
                float v = fmaxf(fmaf(acc0[ct][reg] + bi, sc, sh), 0.f);
                out[(size_t)r * 128 + c] = f2b(v);
            }
            int r2 = rb0 + 16 + reg;
            if (r2 < N_NODES) {
                float v = fmaxf(fmaf(acc1[ct][reg] + bi, sc, sh), 0.f);
                out[(size_t)r2 * 128 + c] = f2b(v);
            }
        }
    }
}

// ---------------------------------------------------------------------------
// Pooling: sorted batch -> run-length accumulate; uint loads (2 feats/lane)
// ---------------------------------------------------------------------------

#define POOL_NODES 64
__global__ __launch_bounds__(256) void pool_kernel(const ushort* __restrict__ h,
                                                   const int* __restrict__ batch,
                                                   float* __restrict__ pooled) {
    __shared__ int gb[POOL_NODES];
    int b = blockIdx.x, t = threadIdx.x;
    int n0 = b * POOL_NODES;
    if (t < POOL_NODES) {
        int n = n0 + t;
        gb[t] = (n < N_NODES) ? batch[n] : -1;
    }
    __syncthreads();
    int f2 = t & 63;
    int q  = t >> 6;
    const uint* hp = (const uint*)h;
    float alo = 0.f, ahi = 0.f;
    int gcur = -1;
    for (int i = q; i < POOL_NODES; i += 4) {
        int n = n0 + i;
        if (n >= N_NODES) break;
        int g = gb[i];
        if (g != gcur) {
            if (gcur >= 0) {
                atomicAdd(&pooled[(size_t)gcur * 128 + f2 * 2], alo);
                atomicAdd(&pooled[(size_t)gcur * 128 + f2 * 2 + 1], ahi);
            }
            gcur = g;
            alo = 0.f; ahi = 0.f;
        }
        uint u = hp[(size_t)n * 64 + f2];
        alo += b2f_lo(u);
        ahi += b2f_hi(u);
    }
    if (gcur >= 0) {
        atomicAdd(&pooled[(size_t)gcur * 128 + f2 * 2], alo);
        atomicAdd(&pooled[(size_t)gcur * 128 + f2 * 2 + 1], ahi);
    }
}

// ---------------------------------------------------------------------------
// Head: counts via binary search on sorted batch, one wave per graph
// ---------------------------------------------------------------------------

__global__ __launch_bounds__(64) void head_kernel(const float* __restrict__ pooled,
                                                  const int* __restrict__ batch,
                                                  const float* __restrict__ w1,
                                                  const float* __restrict__ b1,
                                                  const float* __restrict__ w2,
                                                  const float* __restrict__ b2,
                                                  float* __restrict__ out) {
    int g = blockIdx.x;
    int j = threadIdx.x;
    int lo = 0, hi = N_NODES;
    while (lo < hi) { int m = (lo + hi) >> 1; if (batch[m] <  g) lo = m + 1; else hi = m; }
    int start = lo;
    lo = 0; hi = N_NODES;
    while (lo < hi) { int m = (lo + hi) >> 1; if (batch[m] <= g) lo = m + 1; else hi = m; }
    float inv = 1.0f / fmaxf((float)(lo - start), 1.0f);

    float acc = b1[j];
    #pragma unroll 4
    for (int k = 0; k < 128; ++k)
        acc = fmaf(pooled[(size_t)g * 128 + k] * inv, w1[k * 64 + j], acc);
    float prod = fmaxf(acc, 0.f) * w2[j];
    #pragma unroll
    for (int off = 32; off > 0; off >>= 1)
        prod += __shfl_down(prod, off);
    if (j == 0) out[g] = prod + b2[0];
}

// ---------------------------------------------------------------------------

extern "C" void kernel_launch(void* const* d_in, const int* in_sizes, int n_in,
                              void* d_out, int out_size, void* d_ws, size_t ws_size,
                              hipStream_t stream) {
    const float* x     = (const float*)d_in[0];
    const int*   ei    = (const int*)d_in[1];
    const float* ea    = (const float*)d_in[2];
    const int*   batch = (const int*)d_in[3];
    const float* rel_w[3]  = {(const float*)d_in[4],  (const float*)d_in[11], (const float*)d_in[18]};
    const float* rel_b[3]  = {(const float*)d_in[5],  (const float*)d_in[12], (const float*)d_in[19]};
    const float* root_w[3] = {(const float*)d_in[6],  (const float*)d_in[13], (const float*)d_in[20]};
    const float* bn_g[3]   = {(const float*)d_in[7],  (const float*)d_in[14], (const float*)d_in[21]};
    const float* bn_b[3]   = {(const float*)d_in[8],  (const float*)d_in[15], (const float*)d_in[22]};
    const float* bn_m[3]   = {(const float*)d_in[9],  (const float*)d_in[16], (const float*)d_in[23]};
    const float* bn_v[3]   = {(const float*)d_in[10], (const float*)d_in[17], (const float*)d_in[24]};
    const float* head_w1 = (const float*)d_in[25];
    const float* head_b1 = (const float*)d_in[26];
    const float* head_w2 = (const float*)d_in[27];
    const float* head_b2 = (const float*)d_in[28];
    float* out = (float*)d_out;

    // workspace layout (~104 MB)
    char* ws = (char*)d_ws;
    int*    rowptr  = (int*)(ws + 0);             // N_NODES+1 ints
    int*    counts  = (int*)(ws + 401408);        // SCAN_M ints
    int*    partial = (int*)(ws + 503808);        // SCAN_T ints
    int2*   em      = (int2*)(ws + 524288);       // E int2 (src, bf16 w bits)
    ushort* xb      = (ushort*)(ws + 13631488);   // N*64 bf16
    ushort* h_a     = (ushort*)(ws + 26431488);   // N*128 bf16
    ushort* h_b     = (ushort*)(ws + 52031488);   // N*128 bf16
    ushort* aggb    = (ushort*)(ws + 77631488);   // N*128 bf16 (layer0 uses N*64)
    float*  pooled  = (float*)(ws + 103231488);   // 1024*128 fp32
    ushort* wb      = (ushort*)(ws + 103755776);  // 81920 bf16 (3 W panels)
    // sort scratch aliases aggb region (dead until first agg)
    int2*   emb = (int2*)(ws + 77631488);         // E int2 packed

    ushort* wb0 = wb;            // 128*128
    ushort* wb1 = wb + 16384;    // 128*256
    ushort* wb2 = wb + 49152;    // 128*256

    const int PREP_BLOCKS = NBLK_A + (PREP_TOT + 255) / 256;
    prep_count_kernel<<<PREP_BLOCKS, 256, 0, stream>>>(
        x, (uint*)xb, rel_w[0], root_w[0], rel_w[1], root_w[1], rel_w[2], root_w[2],
        (uint*)wb0, (uint*)wb1, (uint*)wb2, pooled, ei, counts);

    sc_reduce_kernel<<<SCAN_T, 1024, 0, stream>>>(counts, partial);
    sc_apply_kernel<<<SCAN_T, 1024, 0, stream>>>(counts, partial, rowptr);
    bin_scatter_kernel<<<NBLK_A, 256, 0, stream>>>(ei, ea, counts, emb);
    bucket_build_kernel<<<NBUCK, 1024, 0, stream>>>(counts, emb, rowptr, em);

    const int AGG_BLOCKS  = N_NODES / 4;
    const int GEMM_BLOCKS = (N_NODES + 127) / 128;

    agg_kernel<64><<<AGG_BLOCKS, 256, 0, stream>>>(xb, rowptr, em, aggb);
    gemm_mfma<64><<<GEMM_BLOCKS, 256, 0, stream>>>(aggb, xb, wb0, rel_b[0],
                                                   bn_g[0], bn_b[0], bn_m[0], bn_v[0], h_a);
    agg_kernel<128><<<AGG_BLOCKS, 256, 0, stream>>>(h_a, rowptr, em, aggb);
    gemm_mfma<128><<<GEMM_BLOCKS, 256, 0, stream>>>(aggb, h_a, wb1, rel_b[1],
                                                    bn_g[1], bn_b[1], bn_m[1], bn_v[1], h_b);
    agg_kernel<128><<<AGG_BLOCKS, 256, 0, stream>>>(h_b, rowptr, em, aggb);
    gemm_mfma<128><<<GEMM_BLOCKS, 256, 0, stream>>>(aggb, h_b, wb2, rel_b[2],
                                                    bn_g[2], bn_b[2], bn_m[2], bn_v[2], h_a);

    pool_kernel<<<(N_NODES + POOL_NODES - 1) / POOL_NODES, 256, 0, stream>>>(h_a, batch, pooled);
    head_kernel<<<N_GRAPHS, 64, 0, stream>>>(pooled, batch, head_w1, head_b1, head_w2, head_b2, out);
}